// Round 1
// baseline (209.929 us; speedup 1.0000x reference)
//
#include <hip/hip_runtime.h>
#include <hip/hip_bf16.h>
#include <math.h>

#define DIM 192
#define NHD 6
#define HD 32
#define KSZ 7
#define HID 768
#define IMH 128
#define IMW 128
#define NPIX (IMH*IMW)
#define WIN 14
#define KPAD 40

typedef __attribute__((ext_vector_type(8))) short short8;
typedef __attribute__((ext_vector_type(4))) float f32x4;

__device__ __forceinline__ void gl_lds16(const void* g, void* l) {
    __builtin_amdgcn_global_load_lds(
        (const __attribute__((address_space(1))) void*)g,
        (__attribute__((address_space(3))) void*)l, 16, 0, 0);
}

__device__ __forceinline__ short8 cvt8(float4 a, float4 b) {
    union { short8 v; __hip_bfloat16 h[8]; } u;
    u.h[0] = __float2bfloat16(a.x); u.h[1] = __float2bfloat16(a.y);
    u.h[2] = __float2bfloat16(a.z); u.h[3] = __float2bfloat16(a.w);
    u.h[4] = __float2bfloat16(b.x); u.h[5] = __float2bfloat16(b.y);
    u.h[6] = __float2bfloat16(b.z); u.h[7] = __float2bfloat16(b.w);
    return u.v;
}

// stage fp32 weight tile -> bf16 LDS rows of 192 with in-row XOR swizzle.
// LDS[r][kc^(r&7)] = W[r][kc]  (8-elem chunks) -- matches the ds_read side.
template<int ITERS>
__device__ __forceinline__ void stage_w_cvt(const float* __restrict__ Wf, int stride,
                                            __hip_bfloat16* Bs, int tid) {
    #pragma unroll
    for (int i = 0; i < ITERS; i++) {
        int c = i * 256 + tid;
        int r = c / 24, kc = c - r * 24;
        int g = kc ^ (r & 7);
        const float4* src = (const float4*)(Wf + (size_t)r * stride + kc * 8);
        float4 a0 = src[0], a1 = src[1];
        *(short8*)&Bs[r * 192 + g * 8] = cvt8(a0, a1);
    }
}

// ---------------- QKV GEMM with fused LN1 + inline weight cvt ----------------
// tile 128x64, K=192 single-shot, one barrier. A = LN1(x) computed in-block.
// grid: 1152 1D, XCD-remapped so 9 consecutive same-XCD blocks share the A panel.
__global__ __launch_bounds__(256, 2) void qkv_gemm(
    const float* __restrict__ x, const float* __restrict__ lnw, const float* __restrict__ lnb,
    const float* __restrict__ Wf, const float* __restrict__ bias,
    float* __restrict__ qb, __hip_bfloat16* __restrict__ kb, __hip_bfloat16* __restrict__ vb)
{
    __shared__ __hip_bfloat16 As[128 * 192];   // 48 KB
    __shared__ __hip_bfloat16 Bs[64 * 192];    // 24 KB
    int tid = threadIdx.x;
    int wave = tid >> 6, lane = tid & 63;
    int q = lane >> 4, col = lane & 15;
    int wm = (wave >> 1) * 64, wn = (wave & 1) * 32;

    int bid = blockIdx.x;
    int xcd = bid & 7, slot = bid >> 3;          // 144 blocks per XCD
    int mg  = xcd * 16 + slot / 9;               // 16 m-groups per XCD
    int n0i = slot - (slot / 9) * 9;
    int m0 = mg * 128, n0 = n0i * 64;

    // ---- A: LN1(x) -> bf16 swizzled LDS. thread owns half a row (96 cols).
    {
        int lr = tid >> 1, half = tid & 1;
        const float4* xr = (const float4*)(x + (size_t)(m0 + lr) * DIM + half * 96);
        float4 xa[24];
        float s = 0.f;
        #pragma unroll
        for (int i = 0; i < 24; i++) {
            xa[i] = xr[i];
            s += xa[i].x + xa[i].y + xa[i].z + xa[i].w;
        }
        s += __shfl_xor(s, 1);
        float mu = s * (1.0f / DIM);
        float qs = 0.f;
        #pragma unroll
        for (int i = 0; i < 24; i++) {
            float a = xa[i].x - mu, b = xa[i].y - mu, c = xa[i].z - mu, d = xa[i].w - mu;
            qs += a * a + b * b + c * c + d * d;
        }
        qs += __shfl_xor(qs, 1);
        float rstd = rsqrtf(qs * (1.0f / DIM) + 1e-5f);
        const float4* wv = (const float4*)(lnw + half * 96);
        const float4* bv = (const float4*)(lnb + half * 96);
        #pragma unroll
        for (int i2 = 0; i2 < 12; i2++) {
            int kc = half * 12 + i2;
            float4 w0 = wv[i2 * 2], w1 = wv[i2 * 2 + 1];
            float4 b0 = bv[i2 * 2], b1 = bv[i2 * 2 + 1];
            float4 v0 = xa[i2 * 2], v1 = xa[i2 * 2 + 1];
            float4 o0, o1;
            o0.x = (v0.x - mu) * rstd * w0.x + b0.x;
            o0.y = (v0.y - mu) * rstd * w0.y + b0.y;
            o0.z = (v0.z - mu) * rstd * w0.z + b0.z;
            o0.w = (v0.w - mu) * rstd * w0.w + b0.w;
            o1.x = (v1.x - mu) * rstd * w1.x + b1.x;
            o1.y = (v1.y - mu) * rstd * w1.y + b1.y;
            o1.z = (v1.z - mu) * rstd * w1.z + b1.z;
            o1.w = (v1.w - mu) * rstd * w1.w + b1.w;
            int g = kc ^ (lr & 7);
            *(short8*)&As[lr * 192 + g * 8] = cvt8(o0, o1);
        }
    }
    // ---- B: weight tile fp32 -> bf16 swizzled LDS
    stage_w_cvt<6>(Wf + (size_t)n0 * DIM, DIM, Bs, tid);
    __syncthreads();

    f32x4 acc[4][2] = {};
    #pragma unroll
    for (int ks = 0; ks < 6; ks++) {
        short8 af[4], bf[2];
        #pragma unroll
        for (int mi = 0; mi < 4; mi++) {
            int r = wm + mi * 16 + col;
            af[mi] = *(const short8*)&As[r * 192 + (((ks * 4 + q) ^ (r & 7)) * 8)];
        }
        #pragma unroll
        for (int ni = 0; ni < 2; ni++) {
            int r = wn + ni * 16 + col;
            bf[ni] = *(const short8*)&Bs[r * 192 + (((ks * 4 + q) ^ (r & 7)) * 8)];
        }
        #pragma unroll
        for (int mi = 0; mi < 4; mi++)
            #pragma unroll
            for (int ni = 0; ni < 2; ni++)
                acc[mi][ni] = __builtin_amdgcn_mfma_f32_16x16x32_bf16(
                    af[mi], bf[ni], acc[mi][ni], 0, 0, 0);
    }

    #pragma unroll
    for (int mi = 0; mi < 4; mi++) {
        #pragma unroll
        for (int r = 0; r < 4; r++) {
            int m = m0 + wm + mi * 16 + q * 4 + r;
            #pragma unroll
            for (int ni = 0; ni < 2; ni++) {
                int n = n0 + wn + ni * 16 + col;
                float v = acc[mi][ni][r] + bias[n];
                int h18 = n >> 5;
                int sel = h18 / 6;
                int head = h18 - sel * 6;
                size_t idx = ((size_t)head * NPIX + m) * 32 + (n & 31);
                if (sel == 0)      qb[idx] = v * 0.17677669529663687f;
                else if (sel == 1) kb[idx] = __float2bfloat16(v);
                else               vb[idx] = __float2bfloat16(v);
            }
        }
    }
}

// ---------------- FC1 + GELU: tile 128x64, K=192 single-shot, inline weight cvt ----------------
__global__ __launch_bounds__(256) void fc1_gemm(
    const __hip_bfloat16* __restrict__ A, const float* __restrict__ Wf,
    const float* __restrict__ bias, __hip_bfloat16* __restrict__ outb)
{
    __shared__ __hip_bfloat16 As[128 * 192];   // 48 KB
    __shared__ __hip_bfloat16 Bs[64 * 192];    // 24 KB
    int tid = threadIdx.x;
    int wave = tid >> 6, lane = tid & 63;
    int q = lane >> 4, col = lane & 15;
    int wm = (wave >> 1) * 64, wn = (wave & 1) * 32;

    int bid = blockIdx.x;
    int xcd = bid & 7, slot = bid >> 3;          // 192 per XCD
    int mg  = xcd * 16 + slot / 12;
    int n0i = slot - (slot / 12) * 12;
    int m0 = mg * 128, n0 = n0i * 64;

    const __hip_bfloat16* Ab = A + (size_t)m0 * DIM;
    #pragma unroll
    for (int i = 0; i < 12; i++) {
        int c = i * 256 + tid;
        int r = c / 24, kc = c - r * 24;
        int g = kc ^ (r & 7);
        gl_lds16(Ab + r * DIM + g * 8, (char*)As + (i * 256 + wave * 64) * 16);
    }
    stage_w_cvt<6>(Wf + (size_t)n0 * DIM, DIM, Bs, tid);
    __syncthreads();

    f32x4 acc[4][2] = {};
    #pragma unroll
    for (int ks = 0; ks < 6; ks++) {
        short8 af[4], bf[2];
        #pragma unroll
        for (int mi = 0; mi < 4; mi++) {
            int r = wm + mi * 16 + col;
            af[mi] = *(const short8*)&As[r * 192 + (((ks * 4 + q) ^ (r & 7)) * 8)];
        }
        #pragma unroll
        for (int ni = 0; ni < 2; ni++) {
            int r = wn + ni * 16 + col;
            bf[ni] = *(const short8*)&Bs[r * 192 + (((ks * 4 + q) ^ (r & 7)) * 8)];
        }
        #pragma unroll
        for (int mi = 0; mi < 4; mi++)
            #pragma unroll
            for (int ni = 0; ni < 2; ni++)
                acc[mi][ni] = __builtin_amdgcn_mfma_f32_16x16x32_bf16(
                    af[mi], bf[ni], acc[mi][ni], 0, 0, 0);
    }

    #pragma unroll
    for (int mi = 0; mi < 4; mi++) {
        #pragma unroll
        for (int r = 0; r < 4; r++) {
            int m = m0 + wm + mi * 16 + q * 4 + r;
            #pragma unroll
            for (int ni = 0; ni < 2; ni++) {
                int n = n0 + wn + ni * 16 + col;
                float v = acc[mi][ni][r] + bias[n];
                float u = 0.7978845608f * (v + 0.044715f * v * v * v);
                float t = 1.f - 2.f / (__expf(2.f * u) + 1.f);
                v = 0.5f * v * (1.f + t);
                outb[(size_t)m * HID + n] = __float2bfloat16(v);
            }
        }
    }
}

// ---------------- proj + residual + |g1| + fused LN2 (inline weight cvt) ----------------
__global__ __launch_bounds__(256) void proj_ln(
    const __hip_bfloat16* __restrict__ A, const float* __restrict__ Wf,
    const float* __restrict__ bias,
    float* outf, __hip_bfloat16* hb, const float* __restrict__ resid,
    const float* __restrict__ gamma, const int* __restrict__ quality,
    const float* __restrict__ lnw, const float* __restrict__ lnb)
{
    __shared__ __hip_bfloat16 As[64 * 192];    // 24 KB
    __shared__ __hip_bfloat16 Bs[192 * 192];   // 72 KB
    int tid = threadIdx.x;
    int wave = tid >> 6, lane = tid & 63;
    int q = lane >> 4, col = lane & 15;
    int m0 = blockIdx.x * 64;

    const __hip_bfloat16* Ab = A + (size_t)m0 * DIM;
    #pragma unroll
    for (int i = 0; i < 6; i++) {
        int c = i * 256 + tid;
        int r = c / 24, kc = c - r * 24;
        int g = kc ^ (r & 7);
        gl_lds16(Ab + r * DIM + g * 8, (char*)As + (i * 256 + wave * 64) * 16);
    }
    stage_w_cvt<18>(Wf, DIM, Bs, tid);
    __syncthreads();

    f32x4 acc[12] = {};
    #pragma unroll
    for (int ks = 0; ks < 6; ks++) {
        int rA = wave * 16 + col;
        short8 af = *(const short8*)&As[rA * 192 + (((ks * 4 + q) ^ (rA & 7)) * 8)];
        #pragma unroll
        for (int f = 0; f < 12; f++) {
            int rB = f * 16 + col;
            short8 bf = *(const short8*)&Bs[rB * 192 + (((ks * 4 + q) ^ (rB & 7)) * 8)];
            acc[f] = __builtin_amdgcn_mfma_f32_16x16x32_bf16(af, bf, acc[f], 0, 0, 0);
        }
    }

    int s = quality[0] - 1;
    float v[12][4];
    #pragma unroll
    for (int f = 0; f < 12; f++) {
        int n = f * 16 + col;
        float bi = bias[n];
        float g = fabsf(gamma[s * DIM + n]);
        #pragma unroll
        for (int r = 0; r < 4; r++) {
            int m = m0 + wave * 16 + q * 4 + r;
            v[f][r] = resid[(size_t)m * DIM + n] + g * (acc[f][r] + bi);
            outf[(size_t)m * DIM + n] = v[f][r];
        }
    }
    float sm[4] = {}, sq[4] = {};
    #pragma unroll
    for (int f = 0; f < 12; f++)
        #pragma unroll
        for (int r = 0; r < 4; r++) { sm[r] += v[f][r]; sq[r] += v[f][r] * v[f][r]; }
    #pragma unroll
    for (int off = 1; off <= 8; off <<= 1) {
        #pragma unroll
        for (int r = 0; r < 4; r++) {
            sm[r] += __shfl_xor(sm[r], off);
            sq[r] += __shfl_xor(sq[r], off);
        }
    }
    float mu[4], rstd[4];
    #pragma unroll
    for (int r = 0; r < 4; r++) {
        mu[r] = sm[r] * (1.0f / DIM);
        float var = sq[r] * (1.0f / DIM) - mu[r] * mu[r];
        rstd[r] = rsqrtf(var + 1e-5f);
    }
    #pragma unroll
    for (int f = 0; f < 12; f++) {
        int n = f * 16 + col;
        float lw = lnw[n], lb = lnb[n];
        #pragma unroll
        for (int r = 0; r < 4; r++) {
            int m = m0 + wave * 16 + q * 4 + r;
            hb[(size_t)m * DIM + n] = __float2bfloat16((v[f][r] - mu[r]) * rstd[r] * lw + lb);
        }
    }
}

// ---------------- FC2: tile 64x64, BK=192 (4 iters), inline weight cvt, + resid + |g2| ----------------
__global__ __launch_bounds__(256) void fc2_gemm(
    const __hip_bfloat16* __restrict__ A, const float* __restrict__ Wf,
    const float* __restrict__ bias,
    float* outf, const float* __restrict__ resid,
    const float* __restrict__ gamma, const int* __restrict__ quality)
{
    __shared__ __hip_bfloat16 As[64 * 192];   // 24 KB
    __shared__ __hip_bfloat16 Bs[64 * 192];   // 24 KB
    int tid = threadIdx.x;
    int wave = tid >> 6, lane = tid & 63;
    int q = lane >> 4, col = lane & 15;
    int wm = (wave >> 1) * 32, wn = (wave & 1) * 32;

    int bid = blockIdx.x;
    int xcd = bid & 7, slot = bid >> 3;          // 96 per XCD
    int mg  = xcd * 32 + slot / 3;
    int n0i = slot - (slot / 3) * 3;
    int m0 = mg * 64, n0 = n0i * 64;

    f32x4 acc[2][2] = {};
    for (int k0 = 0; k0 < HID; k0 += 192) {
        #pragma unroll
        for (int i = 0; i < 6; i++) {
            int c = i * 256 + tid;
            int r = c / 24, kc = c - r * 24;
            int g = kc ^ (r & 7);
            gl_lds16(A + (size_t)(m0 + r) * HID + k0 + g * 8,
                     (char*)As + (i * 256 + wave * 64) * 16);
        }
        stage_w_cvt<6>(Wf + (size_t)n0 * HID + k0, HID, Bs, tid);
        __syncthreads();
        #pragma unroll
        for (int ks = 0; ks < 6; ks++) {
            short8 af[2], bf[2];
            #pragma unroll
            for (int mi = 0; mi < 2; mi++) {
                int r = wm + mi * 16 + col;
                af[mi] = *(const short8*)&As[r * 192 + (((ks * 4 + q) ^ (r & 7)) * 8)];
            }
            #pragma unroll
            for (int ni = 0; ni < 2; ni++) {
                int r = wn + ni * 16 + col;
                bf[ni] = *(const short8*)&Bs[r * 192 + (((ks * 4 + q) ^ (r & 7)) * 8)];
            }
            #pragma unroll
            for (int mi = 0; mi < 2; mi++)
                #pragma unroll
                for (int ni = 0; ni < 2; ni++)
                    acc[mi][ni] = __builtin_amdgcn_mfma_f32_16x16x32_bf16(
                        af[mi], bf[ni], acc[mi][ni], 0, 0, 0);
        }
        __syncthreads();
    }

    int s = quality[0] - 1;
    #pragma unroll
    for (int mi = 0; mi < 2; mi++) {
        #pragma unroll
        for (int r = 0; r < 4; r++) {
            int m = m0 + wm + mi * 16 + q * 4 + r;
            #pragma unroll
            for (int ni = 0; ni < 2; ni++) {
                int n = n0 + wn + ni * 16 + col;
                float g = fabsf(gamma[s * DIM + n]);
                outf[(size_t)m * DIM + n] =
                    resid[(size_t)m * DIM + n] + g * (acc[mi][ni][r] + bias[n]);
            }
        }
    }
}

// ---------------- Neighborhood attention: bf16 K/V, row-batched online softmax ----------------
__device__ __forceinline__ void unpack8(const __hip_bfloat16* ptr, float* f) {
    short8 s8 = *(const short8*)ptr;
    union { short8 v; unsigned u[4]; } c; c.v = s8;
    #pragma unroll
    for (int w = 0; w < 4; w++) {
        f[2*w]   = __uint_as_float(c.u[w] << 16);
        f[2*w+1] = __uint_as_float(c.u[w] & 0xffff0000u);
    }
}

__global__ __launch_bounds__(256, 4) void attn_kernel3(
    const float* __restrict__ qbuf, const __hip_bfloat16* __restrict__ kbuf,
    const __hip_bfloat16* __restrict__ vbuf, const float* __restrict__ rpb,
    __hip_bfloat16* __restrict__ out)
{
    __shared__ __hip_bfloat16 Ks[WIN * WIN * KPAD];
    __shared__ __hip_bfloat16 Vs[WIN * WIN * KPAD];
    __shared__ float rpbs[169];

    int head = blockIdx.y;
    int tile = blockIdx.x;
    int ti0 = (tile >> 4) * 8;
    int tj0 = (tile & 15) * 8;
    int wi0 = ti0 - 3; wi0 = wi0 < 0 ? 0 : (wi0 > IMH - WIN ? IMH - WIN : wi0);
    int wj0 = tj0 - 3; wj0 = wj0 < 0 ? 0 : (wj0 > IMW - WIN ? IMW - WIN : wj0);

    int tid = threadIdx.x;
    const size_t hbase = (size_t)head * NPIX;

    for (int c = tid; c < 784; c += 256) {
        int i = c / 56, part = c - i * 56;
        int n = i * WIN + (part >> 2);
        int dp = part & 3;
        size_t goff = (hbase + (size_t)(wi0 + i) * IMW + wj0) * 32 + part * 8;
        short8 kk = *(const short8*)(kbuf + goff);
        short8 vv = *(const short8*)(vbuf + goff);
        *(short8*)&Ks[n * KPAD + dp * 8] = kk;
        *(short8*)&Vs[n * KPAD + dp * 8] = vv;
    }
    if (tid < 169) rpbs[tid] = rpb[head * 169 + tid];

    int p   = tid >> 2;
    int sub = tid & 3;
    int pi = ti0 + (p >> 3), pj = tj0 + (p & 7);
    int si = pi - 3; si = si < 0 ? 0 : (si > IMH - KSZ ? IMH - KSZ : si);
    int sj = pj - 3; sj = sj < 0 ? 0 : (sj > IMW - KSZ ? IMW - KSZ : sj);
    int bi = si - wi0, bj = sj - wj0;

    const float4* qp = (const float4*)(qbuf + (hbase + (size_t)(pi * IMW + pj)) * 32 + sub * 8);
    float4 q0 = qp[0], q1 = qp[1];
    float q[8] = {q0.x, q0.y, q0.z, q0.w, q1.x, q1.y, q1.z, q1.w};

    __syncthreads();

    float m = -1e30f, l = 0.f;
    float acc[8] = {};
    #pragma unroll
    for (int ki = 0; ki < KSZ; ki++) {
        int rbase = (bi + ki) * WIN + bj;
        const float* rb = &rpbs[(si + ki - pi + 6) * 13 + (sj - pj + 6)];
        float s7[KSZ];
        #pragma unroll
        for (int kj = 0; kj < KSZ; kj++) {
            float kf[8];
            unpack8(&Ks[(rbase + kj) * KPAD + sub * 8], kf);
            float d = q[0]*kf[0] + q[1]*kf[1] + q[2]*kf[2] + q[3]*kf[3]
                    + q[4]*kf[4] + q[5]*kf[5] + q[6]*kf[6] + q[7]*kf[7];
            d += __shfl_xor(d, 1);
            d += __shfl_xor(d, 2);
            s7[kj] = d + rb[kj];
        }
        float rmax = s7[0];
        #pragma unroll
        for (int kj = 1; kj < KSZ; kj++) rmax = fmaxf(rmax, s7[kj]);
        float mn = fmaxf(m, rmax);
        float co = __expf(m - mn);
        l *= co;
        #pragma unroll
        for (int e = 0; e < 8; e++) acc[e] *= co;
        #pragma unroll
        for (int kj = 0; kj < KSZ; kj++) {
            float pw = __expf(s7[kj] - mn);
            l += pw;
            float vf[8];
            unpack8(&Vs[(rbase + kj) * KPAD + sub * 8], vf);
            #pragma unroll
            for (int e = 0; e < 8; e++) acc[e] += pw * vf[e];
        }
        m = mn;
    }
    float rl = 1.f / l;
    __hip_bfloat16* op = out + (size_t)(pi * IMW + pj) * DIM + head * HD + sub * 8;
    #pragma unroll
    for (int e = 0; e < 8; e++) op[e] = __float2bfloat16(acc[e] * rl);
}

extern "C" void kernel_launch(void* const* d_in, const int* in_sizes, int n_in,
                              void* d_out, int out_size, void* d_ws, size_t ws_size,
                              hipStream_t stream)
{
    const float* x      = (const float*)d_in[0];
    const float* qkv_w  = (const float*)d_in[1];
    const float* qkv_b  = (const float*)d_in[2];
    const float* proj_w = (const float*)d_in[3];
    const float* proj_b = (const float*)d_in[4];
    const float* rpb    = (const float*)d_in[5];
    const float* ln1_w  = (const float*)d_in[6];
    const float* ln1_b  = (const float*)d_in[7];
    const float* ln2_w  = (const float*)d_in[8];
    const float* ln2_b  = (const float*)d_in[9];
    const float* fc1_w  = (const float*)d_in[10];
    const float* fc1_b  = (const float*)d_in[11];
    const float* fc2_w  = (const float*)d_in[12];
    const float* fc2_b  = (const float*)d_in[13];
    const float* gamma1 = (const float*)d_in[14];
    const float* gamma2 = (const float*)d_in[15];
    const int*   quality= (const int*)d_in[16];
    float* out = (float*)d_out;

    char* ws = (char*)d_ws;
    float*          qbuf   = (float*)ws;                         // 12.58 MB [0, 12582912)
    __hip_bfloat16* kbuf   = (__hip_bfloat16*)(ws + 12582912);   // 6.29 MB
    __hip_bfloat16* vbuf   = (__hip_bfloat16*)(ws + 18874368);   // 6.29 MB -> ends 25165824
    __hip_bfloat16* attn_b = (__hip_bfloat16*)(ws + 25165824);   // 6.29 MB -> ends 31457280
    __hip_bfloat16* h      = (__hip_bfloat16*)(ws + 31457280);   // 6.29 MB -> ends 37748736
    __hip_bfloat16* m1     = (__hip_bfloat16*)ws;                // 25.17 MB, aliases q/k/v (dead after attn)

    // 1. QKV GEMM w/ fused LN1 + inline wq cvt -> q fp32 planar (scaled) + k/v bf16 planar
    qkv_gemm<<<1152, 256, 0, stream>>>(x, ln1_w, ln1_b, qkv_w, qkv_b, qbuf, kbuf, vbuf);
    // 2. neighborhood attention -> attn_b (bf16)
    attn_kernel3<<<dim3(256, NHD), 256, 0, stream>>>(qbuf, kbuf, vbuf, rpb, attn_b);
    // 3. proj + residual + LN2 (fused): out = x + |g1|*(attn@wp^T+b), h = LN2(out)
    proj_ln<<<NPIX / 64, 256, 0, stream>>>(
        attn_b, proj_w, proj_b, out, h, x, gamma1, quality, ln2_w, ln2_b);
    // 4. FC1 + GELU (single-K-shot, inline wf1 cvt) -> m1 (bf16)
    fc1_gemm<<<1536, 256, 0, stream>>>(h, fc1_w, fc1_b, m1);
    // 5. FC2 + residual (inline wf2 cvt): out += |g2|*(m1@wf2^T+b)
    fc2_gemm<<<768, 256, 0, stream>>>(m1, fc2_w, fc2_b, out, out, gamma2, quality);
}

// Round 2
// 186.140 us; speedup vs baseline: 1.1278x; 1.1278x over previous
//
#include <hip/hip_runtime.h>
#include <hip/hip_bf16.h>
#include <math.h>

#define DIM 192
#define NHD 6
#define HD 32
#define KSZ 7
#define HID 768
#define IMH 128
#define IMW 128
#define NPIX (IMH*IMW)
#define WIN 14
#define KPAD 40

typedef __attribute__((ext_vector_type(8))) short short8;
typedef __attribute__((ext_vector_type(4))) float f32x4;

// ---------------- fused: weight fp32->bf16 (blocks 0..1727) + LN1 (blocks 1728..) ----------------
__global__ __launch_bounds__(256) void cvt_ln1(
    const float* __restrict__ qw, const float* __restrict__ pw,
    const float* __restrict__ f1, const float* __restrict__ f2,
    __hip_bfloat16* dq, __hip_bfloat16* dp, __hip_bfloat16* df1, __hip_bfloat16* df2,
    const float* __restrict__ x, const float* __restrict__ w, const float* __restrict__ b,
    __hip_bfloat16* __restrict__ hout)
{
    int blk = blockIdx.x, t = threadIdx.x;
    if (blk < 1728) {
        const float* s; __hip_bfloat16* d; int idx;
        if (blk < 432)       { s = qw; d = dq;  idx = blk * 256 + t; }
        else if (blk < 576)  { s = pw; d = dp;  idx = (blk - 432) * 256 + t; }
        else if (blk < 1152) { s = f1; d = df1; idx = (blk - 576) * 256 + t; }
        else                 { s = f2; d = df2; idx = (blk - 1152) * 256 + t; }
        d[idx] = __float2bfloat16(s[idx]);
        return;
    }
    int wid  = ((blk - 1728) * 256 + t) >> 6;
    int lane = t & 63;
    const float* xp = x + (size_t)wid * DIM;
    float v0 = xp[lane], v1 = xp[lane + 64], v2 = xp[lane + 128];
    float s = v0 + v1 + v2;
    #pragma unroll
    for (int off = 32; off > 0; off >>= 1) s += __shfl_down(s, off);
    float mu = __shfl(s, 0) * (1.0f / DIM);
    float d0 = v0 - mu, d1 = v1 - mu, d2 = v2 - mu;
    float q = d0*d0 + d1*d1 + d2*d2;
    #pragma unroll
    for (int off = 32; off > 0; off >>= 1) q += __shfl_down(q, off);
    float rstd = rsqrtf(__shfl(q, 0) * (1.0f / DIM) + 1e-5f);
    __hip_bfloat16* op = hout + (size_t)wid * DIM;
    op[lane]       = __float2bfloat16(d0 * rstd * w[lane]       + b[lane]);
    op[lane + 64]  = __float2bfloat16(d1 * rstd * w[lane + 64]  + b[lane + 64]);
    op[lane + 128] = __float2bfloat16(d2 * rstd * w[lane + 128] + b[lane + 128]);
}

__device__ __forceinline__ void gl_lds16(const void* g, void* l) {
    __builtin_amdgcn_global_load_lds(
        (const __attribute__((address_space(1))) void*)g,
        (__attribute__((address_space(3))) void*)l, 16, 0, 0);
}

// ---------------- single-K-shot GEMM: tile 128x64, K=192 staged whole, ONE barrier ----------------
// mode 0: qkv split -> q fp32 planar (scaled) + k/v bf16 planar
template<int mode>
__global__ __launch_bounds__(256) void gemm_k192(
    const __hip_bfloat16* __restrict__ A, const __hip_bfloat16* __restrict__ W,
    const float* __restrict__ bias,
    float* outf, __hip_bfloat16* outb, __hip_bfloat16* kb, __hip_bfloat16* vb, int N)
{
    __shared__ __hip_bfloat16 As[128 * 192];   // 48 KB
    __shared__ __hip_bfloat16 Bs[64 * 192];    // 24 KB
    int tid = threadIdx.x;
    int wave = tid >> 6, lane = tid & 63;
    int m0 = blockIdx.x * 128, n0 = blockIdx.y * 64;
    int q = lane >> 4, col = lane & 15;
    int wm = (wave >> 1) * 64, wn = (wave & 1) * 32;

    const __hip_bfloat16* Ab = A + (size_t)m0 * 192;
    #pragma unroll
    for (int i = 0; i < 12; i++) {
        int c = i * 256 + tid;
        int r = c / 24, kc = c - r * 24;
        int g = kc ^ (r & 7);
        gl_lds16(Ab + r * 192 + g * 8, (char*)As + (i * 256 + wave * 64) * 16);
    }
    const __hip_bfloat16* Wb = W + (size_t)n0 * 192;
    #pragma unroll
    for (int i = 0; i < 6; i++) {
        int c = i * 256 + tid;
        int r = c / 24, kc = c - r * 24;
        int g = kc ^ (r & 7);
        gl_lds16(Wb + r * 192 + g * 8, (char*)Bs + (i * 256 + wave * 64) * 16);
    }
    __syncthreads();

    f32x4 acc[4][2] = {};
    #pragma unroll
    for (int ks = 0; ks < 6; ks++) {
        short8 af[4], bf[2];
        #pragma unroll
        for (int mi = 0; mi < 4; mi++) {
            int r = wm + mi * 16 + col;
            af[mi] = *(const short8*)&As[r * 192 + (((ks * 4 + q) ^ (r & 7)) * 8)];
        }
        #pragma unroll
        for (int ni = 0; ni < 2; ni++) {
            int r = wn + ni * 16 + col;
            bf[ni] = *(const short8*)&Bs[r * 192 + (((ks * 4 + q) ^ (r & 7)) * 8)];
        }
        #pragma unroll
        for (int mi = 0; mi < 4; mi++)
            #pragma unroll
            for (int ni = 0; ni < 2; ni++)
                acc[mi][ni] = __builtin_amdgcn_mfma_f32_16x16x32_bf16(
                    af[mi], bf[ni], acc[mi][ni], 0, 0, 0);
    }

    #pragma unroll
    for (int mi = 0; mi < 4; mi++) {
        #pragma unroll
        for (int r = 0; r < 4; r++) {
            int m = m0 + wm + mi * 16 + q * 4 + r;
            #pragma unroll
            for (int ni = 0; ni < 2; ni++) {
                int n = n0 + wn + ni * 16 + col;
                float v = acc[mi][ni][r] + bias[n];
                if (mode == 0) {
                    int h18 = n >> 5;
                    int sel = h18 / 6;
                    int head = h18 - sel * 6;
                    size_t idx = ((size_t)head * NPIX + m) * 32 + (n & 31);
                    if (sel == 0)      outf[idx] = v * 0.17677669529663687f;
                    else if (sel == 1) kb[idx] = __float2bfloat16(v);
                    else               vb[idx] = __float2bfloat16(v);
                } else {
                    float u = 0.7978845608f * (v + 0.044715f * v * v * v);
                    float t = 1.f - 2.f / (__expf(2.f * u) + 1.f);
                    v = 0.5f * v * (1.f + t);
                    outb[(size_t)m * N + n] = __float2bfloat16(v);
                }
            }
        }
    }
}

// ---------------- proj + residual + |g1| + fused LN2: 64 rows x 192 cols, one barrier ----------------
__global__ __launch_bounds__(256) void proj_ln(
    const __hip_bfloat16* __restrict__ A, const __hip_bfloat16* __restrict__ W,
    const float* __restrict__ bias,
    float* outf, __hip_bfloat16* hb, const float* __restrict__ resid,
    const float* __restrict__ gamma, const int* __restrict__ quality,
    const float* __restrict__ lnw, const float* __restrict__ lnb)
{
    __shared__ __hip_bfloat16 As[64 * 192];    // 24 KB
    __shared__ __hip_bfloat16 Bs[192 * 192];   // 72 KB
    int tid = threadIdx.x;
    int wave = tid >> 6, lane = tid & 63;
    int q = lane >> 4, col = lane & 15;
    int m0 = blockIdx.x * 64;

    const __hip_bfloat16* Ab = A + (size_t)m0 * 192;
    #pragma unroll
    for (int i = 0; i < 6; i++) {
        int c = i * 256 + tid;
        int r = c / 24, kc = c - r * 24;
        int g = kc ^ (r & 7);
        gl_lds16(Ab + r * 192 + g * 8, (char*)As + (i * 256 + wave * 64) * 16);
    }
    #pragma unroll
    for (int i = 0; i < 18; i++) {
        int c = i * 256 + tid;
        int r = c / 24, kc = c - r * 24;
        int g = kc ^ (r & 7);
        gl_lds16(W + r * 192 + g * 8, (char*)Bs + (i * 256 + wave * 64) * 16);
    }
    __syncthreads();

    f32x4 acc[12] = {};
    #pragma unroll
    for (int ks = 0; ks < 6; ks++) {
        int rA = wave * 16 + col;
        short8 af = *(const short8*)&As[rA * 192 + (((ks * 4 + q) ^ (rA & 7)) * 8)];
        #pragma unroll
        for (int f = 0; f < 12; f++) {
            int rB = f * 16 + col;
            short8 bf = *(const short8*)&Bs[rB * 192 + (((ks * 4 + q) ^ (rB & 7)) * 8)];
            acc[f] = __builtin_amdgcn_mfma_f32_16x16x32_bf16(af, bf, acc[f], 0, 0, 0);
        }
    }

    int s = quality[0] - 1;
    float v[12][4];
    #pragma unroll
    for (int f = 0; f < 12; f++) {
        int n = f * 16 + col;
        float bi = bias[n];
        float g = fabsf(gamma[s * DIM + n]);
        #pragma unroll
        for (int r = 0; r < 4; r++) {
            int m = m0 + wave * 16 + q * 4 + r;
            v[f][r] = resid[(size_t)m * DIM + n] + g * (acc[f][r] + bi);
            outf[(size_t)m * DIM + n] = v[f][r];
        }
    }
    // wave-local LN2 (full 192-col row lives in this wave's 16-lane col group)
    float sm[4] = {}, sq[4] = {};
    #pragma unroll
    for (int f = 0; f < 12; f++)
        #pragma unroll
        for (int r = 0; r < 4; r++) { sm[r] += v[f][r]; sq[r] += v[f][r] * v[f][r]; }
    #pragma unroll
    for (int off = 1; off <= 8; off <<= 1) {
        #pragma unroll
        for (int r = 0; r < 4; r++) {
            sm[r] += __shfl_xor(sm[r], off);
            sq[r] += __shfl_xor(sq[r], off);
        }
    }
    float mu[4], rstd[4];
    #pragma unroll
    for (int r = 0; r < 4; r++) {
        mu[r] = sm[r] * (1.0f / DIM);
        float var = sq[r] * (1.0f / DIM) - mu[r] * mu[r];
        rstd[r] = rsqrtf(var + 1e-5f);
    }
    #pragma unroll
    for (int f = 0; f < 12; f++) {
        int n = f * 16 + col;
        float lw = lnw[n], lb = lnb[n];
        #pragma unroll
        for (int r = 0; r < 4; r++) {
            int m = m0 + wave * 16 + q * 4 + r;
            hb[(size_t)m * DIM + n] = __float2bfloat16((v[f][r] - mu[r]) * rstd[r] * lw + lb);
        }
    }
}

// ---------------- fused MLP: FC1 + GELU (LDS-resident) + FC2 + residual + |g2| ----------------
// 64 rows/block, grid=256 (one block per CU), 512 threads (8 waves).
// LDS: Ms 96KB (gelu out, XOR-oct swizzled), Ws 2x24KB double-buffered weight tiles.
// Counted vmcnt(3) + raw s_barrier keeps weight staging in flight across phases (T3/T4).
__global__ __launch_bounds__(512, 2) void mlp_fused(
    const __hip_bfloat16* __restrict__ A, const __hip_bfloat16* __restrict__ W1,
    const float* __restrict__ b1, const __hip_bfloat16* __restrict__ W2,
    const float* __restrict__ b2, float* __restrict__ outf,
    const float* __restrict__ gamma, const int* __restrict__ quality)
{
    __shared__ __hip_bfloat16 Ms[64 * 768];    // 96 KB
    __shared__ __hip_bfloat16 Ws[2][64 * 192]; // 2 x 24 KB
    int tid = threadIdx.x;
    int wave = tid >> 6, lane = tid & 63;
    int q = lane >> 4, col = lane & 15;
    int m0 = blockIdx.x * 64;
    int wm = (wave >> 1) * 16;   // 4 m-groups of 16 rows
    int wh = (wave & 1);         // n-half

    // per-wave A fragments: 16 rows x 192 K in registers
    short8 af[6];
    {
        const __hip_bfloat16* ap = A + (size_t)(m0 + wm + col) * DIM;
        #pragma unroll
        for (int ks = 0; ks < 6; ks++)
            af[ks] = *(const short8*)(ap + ks * 32 + q * 8);
    }

    auto stage1 = [&](int t, int buf) {   // FC1 weight tile: 64 n-rows x 192 K
        #pragma unroll
        for (int i = 0; i < 3; i++) {
            int c = i * 512 + tid;
            int r = c / 24, kc = c - r * 24;
            int g = kc ^ (r & 7);
            gl_lds16(W1 + (size_t)(t * 64 + r) * DIM + g * 8,
                     (char*)&Ws[buf][0] + (i * 512 + wave * 64) * 16);
        }
    };
    auto stage2 = [&](int ch, int buf) {  // FC2 weight chunk: 192 n-rows x 64 K
        #pragma unroll
        for (int i = 0; i < 3; i++) {
            int idx = i * 512 + tid;
            int r = idx >> 3, o = idx & 7;
            gl_lds16(W2 + (size_t)r * HID + ch * 64 + ((o ^ (r & 7)) * 8),
                     (char*)&Ws[buf][0] + (i * 512 + wave * 64) * 16);
        }
    };

    // ---------------- FC1 phase ----------------
    stage1(0, 0);
    for (int t = 0; t < 12; t++) {
        if (t < 11) stage1(t + 1, (t + 1) & 1);
        else        stage2(0, 0);      // t=11 reads Ws[1]; prefetch FC2 chunk0 into Ws[0]
        asm volatile("s_waitcnt vmcnt(3)" ::: "memory");
        __builtin_amdgcn_s_barrier();
        const __hip_bfloat16* wsb = &Ws[t & 1][0];
        f32x4 acc[2] = {};
        #pragma unroll
        for (int ks = 0; ks < 6; ks++) {
            #pragma unroll
            for (int ni = 0; ni < 2; ni++) {
                int r = wh * 32 + ni * 16 + col;
                short8 bf = *(const short8*)&wsb[r * 192 + (((ks * 4 + q) ^ (r & 7)) * 8)];
                acc[ni] = __builtin_amdgcn_mfma_f32_16x16x32_bf16(af[ks], bf, acc[ni], 0, 0, 0);
            }
        }
        // bias + gelu -> Ms (bf16, per-row XOR-oct swizzle)
        #pragma unroll
        for (int ni = 0; ni < 2; ni++) {
            int n = t * 64 + wh * 32 + ni * 16 + col;
            float bi = b1[n];
            int oct = n >> 3;
            #pragma unroll
            for (int r4 = 0; r4 < 4; r4++) {
                int row = wm + q * 4 + r4;
                float v = acc[ni][r4] + bi;
                float u = 0.7978845608f * (v + 0.044715f * v * v * v);
                float tt = 1.f - 2.f / (__expf(2.f * u) + 1.f);
                v = 0.5f * v * (1.f + tt);
                int osw = (oct & ~7) | ((oct ^ row) & 7);
                *(__hip_bfloat16*)((char*)Ms + row * 1536 + osw * 16 + (n & 7) * 2) =
                    __float2bfloat16(v);
            }
        }
        __builtin_amdgcn_s_barrier();
    }
    __syncthreads();   // Ms visible to all waves (lgkm drain, once)

    // ---------------- FC2 phase ----------------
    int wn2 = wh * 96;
    f32x4 acc2[6] = {};
    for (int ch = 0; ch < 12; ch++) {
        stage2(ch < 11 ? ch + 1 : 11, (ch + 1) & 1);
        asm volatile("s_waitcnt vmcnt(3)" ::: "memory");
        __builtin_amdgcn_s_barrier();
        const __hip_bfloat16* wsb = &Ws[ch & 1][0];
        #pragma unroll
        for (int ks = 0; ks < 2; ks++) {
            int row = wm + col;
            int og = ch * 8 + ks * 4 + q;
            int osw = (og & ~7) | ((og ^ row) & 7);
            short8 a2 = *(const short8*)((char*)Ms + row * 1536 + osw * 16);
            #pragma unroll
            for (int f = 0; f < 6; f++) {
                int r = wn2 + f * 16 + col;
                short8 bf = *(const short8*)&wsb[r * 64 + (((ks * 4 + q) ^ (r & 7)) * 8)];
                acc2[f] = __builtin_amdgcn_mfma_f32_16x16x32_bf16(a2, bf, acc2[f], 0, 0, 0);
            }
        }
        __builtin_amdgcn_s_barrier();
    }
    int s = quality[0] - 1;
    #pragma unroll
    for (int f = 0; f < 6; f++) {
        int n = wn2 + f * 16 + col;
        float g = fabsf(gamma[s * DIM + n]);
        float bi = b2[n];
        #pragma unroll
        for (int r4 = 0; r4 < 4; r4++) {
            int m = m0 + wm + q * 4 + r4;
            outf[(size_t)m * DIM + n] = outf[(size_t)m * DIM + n] + g * (acc2[f][r4] + bi);
        }
    }
}

// ---------------- Neighborhood attention: bf16 K/V, row-batched online softmax ----------------
__device__ __forceinline__ void unpack8(const __hip_bfloat16* ptr, float* f) {
    short8 s8 = *(const short8*)ptr;
    union { short8 v; unsigned u[4]; } c; c.v = s8;
    #pragma unroll
    for (int w = 0; w < 4; w++) {
        f[2*w]   = __uint_as_float(c.u[w] << 16);
        f[2*w+1] = __uint_as_float(c.u[w] & 0xffff0000u);
    }
}

__global__ __launch_bounds__(256, 4) void attn_kernel3(
    const float* __restrict__ qbuf, const __hip_bfloat16* __restrict__ kbuf,
    const __hip_bfloat16* __restrict__ vbuf, const float* __restrict__ rpb,
    __hip_bfloat16* __restrict__ out)
{
    __shared__ __hip_bfloat16 Ks[WIN * WIN * KPAD];
    __shared__ __hip_bfloat16 Vs[WIN * WIN * KPAD];
    __shared__ float rpbs[169];

    int head = blockIdx.y;
    int tile = blockIdx.x;
    int ti0 = (tile >> 4) * 8;
    int tj0 = (tile & 15) * 8;
    int wi0 = ti0 - 3; wi0 = wi0 < 0 ? 0 : (wi0 > IMH - WIN ? IMH - WIN : wi0);
    int wj0 = tj0 - 3; wj0 = wj0 < 0 ? 0 : (wj0 > IMW - WIN ? IMW - WIN : wj0);

    int tid = threadIdx.x;
    const size_t hbase = (size_t)head * NPIX;

    for (int c = tid; c < 784; c += 256) {
        int i = c / 56, part = c - i * 56;
        int n = i * WIN + (part >> 2);
        int dp = part & 3;
        size_t goff = (hbase + (size_t)(wi0 + i) * IMW + wj0) * 32 + part * 8;
        short8 kk = *(const short8*)(kbuf + goff);
        short8 vv = *(const short8*)(vbuf + goff);
        *(short8*)&Ks[n * KPAD + dp * 8] = kk;
        *(short8*)&Vs[n * KPAD + dp * 8] = vv;
    }
    if (tid < 169) rpbs[tid] = rpb[head * 169 + tid];

    int p   = tid >> 2;
    int sub = tid & 3;
    int pi = ti0 + (p >> 3), pj = tj0 + (p & 7);
    int si = pi - 3; si = si < 0 ? 0 : (si > IMH - KSZ ? IMH - KSZ : si);
    int sj = pj - 3; sj = sj < 0 ? 0 : (sj > IMW - KSZ ? IMW - KSZ : sj);
    int bi = si - wi0, bj = sj - wj0;

    const float4* qp = (const float4*)(qbuf + (hbase + (size_t)(pi * IMW + pj)) * 32 + sub * 8);
    float4 q0 = qp[0], q1 = qp[1];
    float q[8] = {q0.x, q0.y, q0.z, q0.w, q1.x, q1.y, q1.z, q1.w};

    __syncthreads();

    float m = -1e30f, l = 0.f;
    float acc[8] = {};
    #pragma unroll
    for (int ki = 0; ki < KSZ; ki++) {
        int rbase = (bi + ki) * WIN + bj;
        const float* rb = &rpbs[(si + ki - pi + 6) * 13 + (sj - pj + 6)];
        float s7[KSZ];
        #pragma unroll
        for (int kj = 0; kj < KSZ; kj++) {
            float kf[8];
            unpack8(&Ks[(rbase + kj) * KPAD + sub * 8], kf);
            float d = q[0]*kf[0] + q[1]*kf[1] + q[2]*kf[2] + q[3]*kf[3]
                    + q[4]*kf[4] + q[5]*kf[5] + q[6]*kf[6] + q[7]*kf[7];
            d += __shfl_xor(d, 1);
            d += __shfl_xor(d, 2);
            s7[kj] = d + rb[kj];
        }
        float rmax = s7[0];
        #pragma unroll
        for (int kj = 1; kj < KSZ; kj++) rmax = fmaxf(rmax, s7[kj]);
        float mn = fmaxf(m, rmax);
        float co = __expf(m - mn);
        l *= co;
        #pragma unroll
        for (int e = 0; e < 8; e++) acc[e] *= co;
        #pragma unroll
        for (int kj = 0; kj < KSZ; kj++) {
            float pw = __expf(s7[kj] - mn);
            l += pw;
            float vf[8];
            unpack8(&Vs[(rbase + kj) * KPAD + sub * 8], vf);
            #pragma unroll
            for (int e = 0; e < 8; e++) acc[e] += pw * vf[e];
        }
        m = mn;
    }
    float rl = 1.f / l;
    __hip_bfloat16* op = out + (size_t)(pi * IMW + pj) * DIM + head * HD + sub * 8;
    #pragma unroll
    for (int e = 0; e < 8; e++) op[e] = __float2bfloat16(acc[e] * rl);
}

extern "C" void kernel_launch(void* const* d_in, const int* in_sizes, int n_in,
                              void* d_out, int out_size, void* d_ws, size_t ws_size,
                              hipStream_t stream)
{
    const float* x      = (const float*)d_in[0];
    const float* qkv_w  = (const float*)d_in[1];
    const float* qkv_b  = (const float*)d_in[2];
    const float* proj_w = (const float*)d_in[3];
    const float* proj_b = (const float*)d_in[4];
    const float* rpb    = (const float*)d_in[5];
    const float* ln1_w  = (const float*)d_in[6];
    const float* ln1_b  = (const float*)d_in[7];
    const float* ln2_w  = (const float*)d_in[8];
    const float* ln2_b  = (const float*)d_in[9];
    const float* fc1_w  = (const float*)d_in[10];
    const float* fc1_b  = (const float*)d_in[11];
    const float* fc2_w  = (const float*)d_in[12];
    const float* fc2_b  = (const float*)d_in[13];
    const float* gamma1 = (const float*)d_in[14];
    const float* gamma2 = (const float*)d_in[15];
    const int*   quality= (const int*)d_in[16];
    float* out = (float*)d_out;

    char* ws = (char*)d_ws;
    float*          qbuf   = (float*)ws;                         // 12.58 MB
    __hip_bfloat16* kbuf   = (__hip_bfloat16*)(ws + 12582912);   // 6.29 MB
    __hip_bfloat16* vbuf   = (__hip_bfloat16*)(ws + 18874368);   // 6.29 MB
    __hip_bfloat16* h      = (__hip_bfloat16*)(ws + 37748736);
    __hip_bfloat16* attn_b = (__hip_bfloat16*)(ws + 44040192);
    __hip_bfloat16* wq     = (__hip_bfloat16*)(ws + 50331648);
    __hip_bfloat16* wp     = (__hip_bfloat16*)(ws + 50552832);
    __hip_bfloat16* wf1    = (__hip_bfloat16*)(ws + 50626560);
    __hip_bfloat16* wf2    = (__hip_bfloat16*)(ws + 50921472);

    // 0. weights->bf16 + LN1 fused
    cvt_ln1<<<1728 + NPIX / 4, 256, 0, stream>>>(
        qkv_w, proj_w, fc1_w, fc2_w, wq, wp, wf1, wf2, x, ln1_w, ln1_b, h);
    // 1. QKV GEMM (single-K-shot 128x64) -> q fp32 planar (scaled) + k/v bf16 planar
    gemm_k192<0><<<dim3(NPIX / 128, 9), 256, 0, stream>>>(
        h, wq, qkv_b, qbuf, nullptr, kbuf, vbuf, 576);
    // 2. neighborhood attention -> attn_b (bf16)
    attn_kernel3<<<dim3(256, NHD), 256, 0, stream>>>(qbuf, kbuf, vbuf, rpb, attn_b);
    // 3. proj + residual + LN2 (fused): out = x + |g1|*(attn@wp^T+b), h = LN2(out)
    proj_ln<<<NPIX / 64, 256, 0, stream>>>(
        attn_b, wp, proj_b, out, h, x, gamma1, quality, ln2_w, ln2_b);
    // 4+5. fused MLP: FC1+GELU in LDS, FC2 + residual + |g2| (no m1 round-trip)
    mlp_fused<<<256, 512, 0, stream>>>(
        h, wf1, fc1_b, wf2, fc2_b, out, gamma2, quality);
}

// Round 3
// 175.930 us; speedup vs baseline: 1.1933x; 1.0580x over previous
//
#include <hip/hip_runtime.h>
#include <hip/hip_bf16.h>
#include <math.h>

#define DIM 192
#define NHD 6
#define HD 32
#define KSZ 7
#define HID 768
#define IMH 128
#define IMW 128
#define NPIX (IMH*IMW)
#define WIN 14
#define KPAD 40

typedef __attribute__((ext_vector_type(8))) short short8;
typedef __attribute__((ext_vector_type(4))) float f32x4;

// ---------------- fused: weight fp32->bf16 (vectorized, blocks 0..431) + LN1 (blocks 432..) ----------------
__global__ __launch_bounds__(256) void cvt_ln1(
    const float* __restrict__ qw, const float* __restrict__ pw,
    const float* __restrict__ f1, const float* __restrict__ f2,
    __hip_bfloat16* dq, __hip_bfloat16* dp, __hip_bfloat16* df1, __hip_bfloat16* df2,
    const float* __restrict__ x, const float* __restrict__ w, const float* __restrict__ b,
    __hip_bfloat16* __restrict__ hout)
{
    int blk = blockIdx.x, t = threadIdx.x;
    if (blk < 432) {
        // 1024 elems/block, 4/thread via float4
        const float* s; __hip_bfloat16* d; int base;
        if (blk < 108)      { s = qw; d = dq;  base = blk * 1024; }
        else if (blk < 144) { s = pw; d = dp;  base = (blk - 108) * 1024; }
        else if (blk < 288) { s = f1; d = df1; base = (blk - 144) * 1024; }
        else                { s = f2; d = df2; base = (blk - 288) * 1024; }
        int idx = base + t * 4;
        float4 v4 = *(const float4*)(s + idx);
        union { ushort4 u; __hip_bfloat16 h[4]; } o;
        o.h[0] = __float2bfloat16(v4.x); o.h[1] = __float2bfloat16(v4.y);
        o.h[2] = __float2bfloat16(v4.z); o.h[3] = __float2bfloat16(v4.w);
        *(ushort4*)&d[idx] = o.u;
        return;
    }
    int wid  = ((blk - 432) * 256 + t) >> 6;
    int lane = t & 63;
    const float* xp = x + (size_t)wid * DIM;
    float v0 = xp[lane], v1 = xp[lane + 64], v2 = xp[lane + 128];
    float s = v0 + v1 + v2;
    #pragma unroll
    for (int off = 32; off > 0; off >>= 1) s += __shfl_down(s, off);
    float mu = __shfl(s, 0) * (1.0f / DIM);
    float d0 = v0 - mu, d1 = v1 - mu, d2 = v2 - mu;
    float q = d0*d0 + d1*d1 + d2*d2;
    #pragma unroll
    for (int off = 32; off > 0; off >>= 1) q += __shfl_down(q, off);
    float rstd = rsqrtf(__shfl(q, 0) * (1.0f / DIM) + 1e-5f);
    __hip_bfloat16* op = hout + (size_t)wid * DIM;
    op[lane]       = __float2bfloat16(d0 * rstd * w[lane]       + b[lane]);
    op[lane + 64]  = __float2bfloat16(d1 * rstd * w[lane + 64]  + b[lane + 64]);
    op[lane + 128] = __float2bfloat16(d2 * rstd * w[lane + 128] + b[lane + 128]);
}

__device__ __forceinline__ void gl_lds16(const void* g, void* l) {
    __builtin_amdgcn_global_load_lds(
        (const __attribute__((address_space(1))) void*)g,
        (__attribute__((address_space(3))) void*)l, 16, 0, 0);
}

// ---------------- single-K-shot QKV GEMM: tile 128x64, K=192 staged whole, ONE barrier ----------------
__global__ __launch_bounds__(256) void qkv_gemm(
    const __hip_bfloat16* __restrict__ A, const __hip_bfloat16* __restrict__ W,
    const float* __restrict__ bias,
    float* __restrict__ qb, __hip_bfloat16* __restrict__ kb, __hip_bfloat16* __restrict__ vb)
{
    __shared__ __hip_bfloat16 As[128 * 192];   // 48 KB
    __shared__ __hip_bfloat16 Bs[64 * 192];    // 24 KB
    int tid = threadIdx.x;
    int wave = tid >> 6, lane = tid & 63;
    int m0 = blockIdx.x * 128, n0 = blockIdx.y * 64;
    int q = lane >> 4, col = lane & 15;
    int wm = (wave >> 1) * 64, wn = (wave & 1) * 32;

    const __hip_bfloat16* Ab = A + (size_t)m0 * 192;
    #pragma unroll
    for (int i = 0; i < 12; i++) {
        int c = i * 256 + tid;
        int r = c / 24, kc = c - r * 24;
        int g = kc ^ (r & 7);
        gl_lds16(Ab + r * 192 + g * 8, (char*)As + (i * 256 + wave * 64) * 16);
    }
    const __hip_bfloat16* Wb = W + (size_t)n0 * 192;
    #pragma unroll
    for (int i = 0; i < 6; i++) {
        int c = i * 256 + tid;
        int r = c / 24, kc = c - r * 24;
        int g = kc ^ (r & 7);
        gl_lds16(Wb + r * 192 + g * 8, (char*)Bs + (i * 256 + wave * 64) * 16);
    }
    __syncthreads();

    f32x4 acc[4][2] = {};
    #pragma unroll
    for (int ks = 0; ks < 6; ks++) {
        short8 af[4], bf[2];
        #pragma unroll
        for (int mi = 0; mi < 4; mi++) {
            int r = wm + mi * 16 + col;
            af[mi] = *(const short8*)&As[r * 192 + (((ks * 4 + q) ^ (r & 7)) * 8)];
        }
        #pragma unroll
        for (int ni = 0; ni < 2; ni++) {
            int r = wn + ni * 16 + col;
            bf[ni] = *(const short8*)&Bs[r * 192 + (((ks * 4 + q) ^ (r & 7)) * 8)];
        }
        #pragma unroll
        for (int mi = 0; mi < 4; mi++)
            #pragma unroll
            for (int ni = 0; ni < 2; ni++)
                acc[mi][ni] = __builtin_amdgcn_mfma_f32_16x16x32_bf16(
                    af[mi], bf[ni], acc[mi][ni], 0, 0, 0);
    }

    #pragma unroll
    for (int mi = 0; mi < 4; mi++) {
        #pragma unroll
        for (int r = 0; r < 4; r++) {
            int m = m0 + wm + mi * 16 + q * 4 + r;
            #pragma unroll
            for (int ni = 0; ni < 2; ni++) {
                int n = n0 + wn + ni * 16 + col;
                float v = acc[mi][ni][r] + bias[n];
                int h18 = n >> 5;
                int sel = h18 / 6;
                int head = h18 - sel * 6;
                size_t idx = ((size_t)head * NPIX + m) * 32 + (n & 31);
                if (sel == 0)      qb[idx] = v * 0.17677669529663687f;
                else if (sel == 1) kb[idx] = __float2bfloat16(v);
                else               vb[idx] = __float2bfloat16(v);
            }
        }
    }
}

// ---------------- fused tail: proj + resid + |g1| + LN2 + FC1 + GELU + FC2 + resid + |g2| ----------------
// 64 rows/block, grid=256 (one block per CU), 512 threads (8 waves).
// LDS arena 96KB: [0,72K)=Bsp(proj W) then Ms rows 0..47; [72K,96K)=As/Hs then Ms rows 48..63.
// Ws 2x24KB double-buffered weight tiles (counted vmcnt(3) + raw s_barrier, proven in r1 mlp_fused).
// The post-attn residual v[6][4] stays in registers across all 3 GEMM phases (proj/FC2 layouts identical).
__global__ __launch_bounds__(512, 2) void tail_fused(
    const __hip_bfloat16* __restrict__ A, const __hip_bfloat16* __restrict__ Wp,
    const float* __restrict__ pb, const float* __restrict__ resid,
    const float* __restrict__ gamma1, const float* __restrict__ ln2w, const float* __restrict__ ln2b,
    const __hip_bfloat16* __restrict__ W1, const float* __restrict__ b1,
    const __hip_bfloat16* __restrict__ W2, const float* __restrict__ b2,
    const float* __restrict__ gamma2, const int* __restrict__ quality,
    float* __restrict__ outf)
{
    __shared__ __hip_bfloat16 arena[64 * 768];     // 96 KB
    __shared__ __hip_bfloat16 Wsb[2][64 * 192];    // 2 x 24 KB
    __shared__ float lnred[2][64][2];              // 1 KB
    __hip_bfloat16* Bsp = arena;                   // 72 KB: 192x192 proj weight
    __hip_bfloat16* Hs  = arena + 192 * 192;       // 24 KB: attn A-tile, then LN2(h)

    int tid = threadIdx.x;
    int wave = tid >> 6, lane = tid & 63;
    int q = lane >> 4, col = lane & 15;
    int wm = (wave >> 1) * 16, wh = wave & 1;
    int m0 = blockIdx.x * 64;

    // ---- stage attn tile (into Hs region) + proj weight (Bsp)
    const __hip_bfloat16* Ab = A + (size_t)m0 * DIM;
    #pragma unroll
    for (int i = 0; i < 3; i++) {
        int c = i * 512 + tid;
        int r = c / 24, kc = c - r * 24;
        gl_lds16(Ab + r * DIM + (kc ^ (r & 7)) * 8, (char*)Hs + (i * 512 + wave * 64) * 16);
    }
    #pragma unroll
    for (int i = 0; i < 9; i++) {
        int c = i * 512 + tid;
        int r = c / 24, kc = c - r * 24;
        gl_lds16(Wp + (size_t)r * DIM + (kc ^ (r & 7)) * 8, (char*)Bsp + (i * 512 + wave * 64) * 16);
    }
    __syncthreads();

    // ---- proj GEMM: each wave 16 rows x 96 cols
    f32x4 acc[6] = {};
    #pragma unroll
    for (int ks = 0; ks < 6; ks++) {
        int rA = wm + col;
        short8 af = *(const short8*)&Hs[rA * DIM + (((ks * 4 + q) ^ (rA & 7)) * 8)];
        #pragma unroll
        for (int f = 0; f < 6; f++) {
            int rB = wh * 96 + f * 16 + col;
            short8 bf = *(const short8*)&Bsp[rB * DIM + (((ks * 4 + q) ^ (rB & 7)) * 8)];
            acc[f] = __builtin_amdgcn_mfma_f32_16x16x32_bf16(af, bf, acc[f], 0, 0, 0);
        }
    }

    // ---- residual + |g1|; LN2 stats (cross-wh via lnred)
    int s = quality[0] - 1;
    float v[6][4];
    float sm[4] = {}, sq[4] = {};
    #pragma unroll
    for (int f = 0; f < 6; f++) {
        int n = wh * 96 + f * 16 + col;
        float bi = pb[n];
        float g = fabsf(gamma1[s * DIM + n]);
        #pragma unroll
        for (int r = 0; r < 4; r++) {
            int m = m0 + wm + q * 4 + r;
            v[f][r] = resid[(size_t)m * DIM + n] + g * (acc[f][r] + bi);
            sm[r] += v[f][r]; sq[r] += v[f][r] * v[f][r];
        }
    }
    #pragma unroll
    for (int off = 1; off <= 8; off <<= 1)
        #pragma unroll
        for (int r = 0; r < 4; r++) {
            sm[r] += __shfl_xor(sm[r], off);
            sq[r] += __shfl_xor(sq[r], off);
        }
    if (col == 0) {
        #pragma unroll
        for (int r = 0; r < 4; r++) {
            lnred[wh][wm + q * 4 + r][0] = sm[r];
            lnred[wh][wm + q * 4 + r][1] = sq[r];
        }
    }
    __syncthreads();   // also: all As reads done before Hs overwrite below
    float mu[4], rstd[4];
    #pragma unroll
    for (int r = 0; r < 4; r++) {
        int ml = wm + q * 4 + r;
        float smt = lnred[0][ml][0] + lnred[1][ml][0];
        float sqt = lnred[0][ml][1] + lnred[1][ml][1];
        mu[r] = smt * (1.0f / DIM);
        float var = sqt * (1.0f / DIM) - mu[r] * mu[r];
        rstd[r] = rsqrtf(var + 1e-5f);
    }
    // ---- write LN2(h) into Hs (GEMM-swizzled)
    #pragma unroll
    for (int f = 0; f < 6; f++) {
        int n = wh * 96 + f * 16 + col;
        float lw = ln2w[n], lb = ln2b[n];
        #pragma unroll
        for (int r = 0; r < 4; r++) {
            int ml = wm + q * 4 + r;
            Hs[ml * DIM + (((n >> 3) ^ (ml & 7)) * 8) + (n & 7)] =
                __float2bfloat16((v[f][r] - mu[r]) * rstd[r] * lw + lb);
        }
    }
    __syncthreads();
    // ---- load per-wave FC1 A fragments from Hs
    short8 af1[6];
    {
        int rowA = wm + col;
        #pragma unroll
        for (int ks = 0; ks < 6; ks++)
            af1[ks] = *(const short8*)&Hs[rowA * DIM + (((ks * 4 + q) ^ (rowA & 7)) * 8)];
    }
    __syncthreads();   // all af1 loaded before Ms overwrites arena

    auto stage1 = [&](int t, int buf) {   // FC1 weight tile: 64 n-rows x 192 K
        #pragma unroll
        for (int i = 0; i < 3; i++) {
            int c = i * 512 + tid;
            int r = c / 24, kc = c - r * 24;
            gl_lds16(W1 + (size_t)(t * 64 + r) * DIM + (kc ^ (r & 7)) * 8,
                     (char*)&Wsb[buf][0] + (i * 512 + wave * 64) * 16);
        }
    };
    auto stage2 = [&](int ch, int buf) {  // FC2 weight chunk: 192 n-rows x 64 K
        #pragma unroll
        for (int i = 0; i < 3; i++) {
            int idx = i * 512 + tid;
            int r = idx >> 3, o = idx & 7;
            gl_lds16(W2 + (size_t)r * HID + ch * 64 + ((o ^ (r & 7)) * 8),
                     (char*)&Wsb[buf][0] + (i * 512 + wave * 64) * 16);
        }
    };
    __hip_bfloat16* Ms = arena;   // 64 rows x 768, row stride 1536 B, XOR-oct swizzle

    // ---------------- FC1 phase ----------------
    stage1(0, 0);
    for (int t = 0; t < 12; t++) {
        if (t < 11) stage1(t + 1, (t + 1) & 1);
        else        stage2(0, 0);
        asm volatile("s_waitcnt vmcnt(3)" ::: "memory");
        __builtin_amdgcn_s_barrier();
        const __hip_bfloat16* wsb = &Wsb[t & 1][0];
        f32x4 a1[2] = {};
        #pragma unroll
        for (int ks = 0; ks < 6; ks++) {
            #pragma unroll
            for (int ni = 0; ni < 2; ni++) {
                int r = wh * 32 + ni * 16 + col;
                short8 bf = *(const short8*)&wsb[r * DIM + (((ks * 4 + q) ^ (r & 7)) * 8)];
                a1[ni] = __builtin_amdgcn_mfma_f32_16x16x32_bf16(af1[ks], bf, a1[ni], 0, 0, 0);
            }
        }
        #pragma unroll
        for (int ni = 0; ni < 2; ni++) {
            int n = t * 64 + wh * 32 + ni * 16 + col;
            float bi = b1[n];
            int oct = n >> 3;
            #pragma unroll
            for (int r4 = 0; r4 < 4; r4++) {
                int row = wm + q * 4 + r4;
                float vv = a1[ni][r4] + bi;
                float u = 0.7978845608f * (vv + 0.044715f * vv * vv * vv);
                float tt = 1.f - 2.f / (__expf(2.f * u) + 1.f);
                vv = 0.5f * vv * (1.f + tt);
                int osw = (oct & ~7) | ((oct ^ row) & 7);
                *(__hip_bfloat16*)((char*)Ms + row * 1536 + osw * 16 + (n & 7) * 2) =
                    __float2bfloat16(vv);
            }
        }
        __builtin_amdgcn_s_barrier();
    }
    __syncthreads();

    // ---------------- FC2 phase ----------------
    int wn2 = wh * 96;
    f32x4 acc2[6] = {};
    for (int ch = 0; ch < 12; ch++) {
        stage2(ch < 11 ? ch + 1 : 11, (ch + 1) & 1);
        asm volatile("s_waitcnt vmcnt(3)" ::: "memory");
        __builtin_amdgcn_s_barrier();
        const __hip_bfloat16* wsb = &Wsb[ch & 1][0];
        #pragma unroll
        for (int ks = 0; ks < 2; ks++) {
            int row = wm + col;
            int og = ch * 8 + ks * 4 + q;
            int osw = (og & ~7) | ((og ^ row) & 7);
            short8 a2 = *(const short8*)((char*)Ms + row * 1536 + osw * 16);
            #pragma unroll
            for (int f = 0; f < 6; f++) {
                int r = wn2 + f * 16 + col;
                short8 bf = *(const short8*)&wsb[r * 64 + (((ks * 4 + q) ^ (r & 7)) * 8)];
                acc2[f] = __builtin_amdgcn_mfma_f32_16x16x32_bf16(a2, bf, acc2[f], 0, 0, 0);
            }
        }
        __builtin_amdgcn_s_barrier();
    }
    // ---- final: out = v + |g2|*(fc2+b2)  (v still in registers, layouts identical)
    #pragma unroll
    for (int f = 0; f < 6; f++) {
        int n = wn2 + f * 16 + col;
        float g = fabsf(gamma2[s * DIM + n]);
        float bi = b2[n];
        #pragma unroll
        for (int r4 = 0; r4 < 4; r4++) {
            int m = m0 + wm + q * 4 + r4;
            outf[(size_t)m * DIM + n] = v[f][r4] + g * (acc2[f][r4] + bi);
        }
    }
}

// ---------------- Neighborhood attention: bf16 K/V, row-batched online softmax ----------------
__device__ __forceinline__ void unpack8(const __hip_bfloat16* ptr, float* f) {
    short8 s8 = *(const short8*)ptr;
    union { short8 v; unsigned u[4]; } c; c.v = s8;
    #pragma unroll
    for (int w = 0; w < 4; w++) {
        f[2*w]   = __uint_as_float(c.u[w] << 16);
        f[2*w+1] = __uint_as_float(c.u[w] & 0xffff0000u);
    }
}

__global__ __launch_bounds__(256, 4) void attn_kernel3(
    const float* __restrict__ qbuf, const __hip_bfloat16* __restrict__ kbuf,
    const __hip_bfloat16* __restrict__ vbuf, const float* __restrict__ rpb,
    __hip_bfloat16* __restrict__ out)
{
    __shared__ __hip_bfloat16 Ks[WIN * WIN * KPAD];
    __shared__ __hip_bfloat16 Vs[WIN * WIN * KPAD];
    __shared__ float rpbs[169];

    int head = blockIdx.y;
    int tile = blockIdx.x;
    int ti0 = (tile >> 4) * 8;
    int tj0 = (tile & 15) * 8;
    int wi0 = ti0 - 3; wi0 = wi0 < 0 ? 0 : (wi0 > IMH - WIN ? IMH - WIN : wi0);
    int wj0 = tj0 - 3; wj0 = wj0 < 0 ? 0 : (wj0 > IMW - WIN ? IMW - WIN : wj0);

    int tid = threadIdx.x;
    const size_t hbase = (size_t)head * NPIX;

    for (int c = tid; c < 784; c += 256) {
        int i = c / 56, part = c - i * 56;
        int n = i * WIN + (part >> 2);
        int dp = part & 3;
        size_t goff = (hbase + (size_t)(wi0 + i) * IMW + wj0) * 32 + part * 8;
        short8 kk = *(const short8*)(kbuf + goff);
        short8 vv = *(const short8*)(vbuf + goff);
        *(short8*)&Ks[n * KPAD + dp * 8] = kk;
        *(short8*)&Vs[n * KPAD + dp * 8] = vv;
    }
    if (tid < 169) rpbs[tid] = rpb[head * 169 + tid];

    int p   = tid >> 2;
    int sub = tid & 3;
    int pi = ti0 + (p >> 3), pj = tj0 + (p & 7);
    int si = pi - 3; si = si < 0 ? 0 : (si > IMH - KSZ ? IMH - KSZ : si);
    int sj = pj - 3; sj = sj < 0 ? 0 : (sj > IMW - KSZ ? IMW - KSZ : sj);
    int bi = si - wi0, bj = sj - wj0;

    const float4* qp = (const float4*)(qbuf + (hbase + (size_t)(pi * IMW + pj)) * 32 + sub * 8);
    float4 q0 = qp[0], q1 = qp[1];
    float q[8] = {q0.x, q0.y, q0.z, q0.w, q1.x, q1.y, q1.z, q1.w};

    __syncthreads();

    float m = -1e30f, l = 0.f;
    float acc[8] = {};
    #pragma unroll
    for (int ki = 0; ki < KSZ; ki++) {
        int rbase = (bi + ki) * WIN + bj;
        const float* rb = &rpbs[(si + ki - pi + 6) * 13 + (sj - pj + 6)];
        float s7[KSZ];
        #pragma unroll
        for (int kj = 0; kj < KSZ; kj++) {
            float kf[8];
            unpack8(&Ks[(rbase + kj) * KPAD + sub * 8], kf);
            float d = q[0]*kf[0] + q[1]*kf[1] + q[2]*kf[2] + q[3]*kf[3]
                    + q[4]*kf[4] + q[5]*kf[5] + q[6]*kf[6] + q[7]*kf[7];
            d += __shfl_xor(d, 1);
            d += __shfl_xor(d, 2);
            s7[kj] = d + rb[kj];
        }
        float rmax = s7[0];
        #pragma unroll
        for (int kj = 1; kj < KSZ; kj++) rmax = fmaxf(rmax, s7[kj]);
        float mn = fmaxf(m, rmax);
        float co = __expf(m - mn);
        l *= co;
        #pragma unroll
        for (int e = 0; e < 8; e++) acc[e] *= co;
        #pragma unroll
        for (int kj = 0; kj < KSZ; kj++) {
            float pw = __expf(s7[kj] - mn);
            l += pw;
            float vf[8];
            unpack8(&Vs[(rbase + kj) * KPAD + sub * 8], vf);
            #pragma unroll
            for (int e = 0; e < 8; e++) acc[e] += pw * vf[e];
        }
        m = mn;
    }
    float rl = 1.f / l;
    __hip_bfloat16* op = out + (size_t)(pi * IMW + pj) * DIM + head * HD + sub * 8;
    #pragma unroll
    for (int e = 0; e < 8; e++) op[e] = __float2bfloat16(acc[e] * rl);
}

extern "C" void kernel_launch(void* const* d_in, const int* in_sizes, int n_in,
                              void* d_out, int out_size, void* d_ws, size_t ws_size,
                              hipStream_t stream)
{
    const float* x      = (const float*)d_in[0];
    const float* qkv_w  = (const float*)d_in[1];
    const float* qkv_b  = (const float*)d_in[2];
    const float* proj_w = (const float*)d_in[3];
    const float* proj_b = (const float*)d_in[4];
    const float* rpb    = (const float*)d_in[5];
    const float* ln1_w  = (const float*)d_in[6];
    const float* ln1_b  = (const float*)d_in[7];
    const float* ln2_w  = (const float*)d_in[8];
    const float* ln2_b  = (const float*)d_in[9];
    const float* fc1_w  = (const float*)d_in[10];
    const float* fc1_b  = (const float*)d_in[11];
    const float* fc2_w  = (const float*)d_in[12];
    const float* fc2_b  = (const float*)d_in[13];
    const float* gamma1 = (const float*)d_in[14];
    const float* gamma2 = (const float*)d_in[15];
    const int*   quality= (const int*)d_in[16];
    float* out = (float*)d_out;

    char* ws = (char*)d_ws;
    float*          qbuf   = (float*)ws;                         // 12.58 MB
    __hip_bfloat16* kbuf   = (__hip_bfloat16*)(ws + 12582912);   // 6.29 MB
    __hip_bfloat16* vbuf   = (__hip_bfloat16*)(ws + 18874368);   // 6.29 MB
    __hip_bfloat16* h      = (__hip_bfloat16*)(ws + 37748736);   // LN1 out (qkv input)
    __hip_bfloat16* attn_b = (__hip_bfloat16*)(ws + 44040192);
    __hip_bfloat16* wq     = (__hip_bfloat16*)(ws + 50331648);
    __hip_bfloat16* wp     = (__hip_bfloat16*)(ws + 50552832);
    __hip_bfloat16* wf1    = (__hip_bfloat16*)(ws + 50626560);
    __hip_bfloat16* wf2    = (__hip_bfloat16*)(ws + 50921472);

    // 0. weights->bf16 (vectorized) + LN1 fused
    cvt_ln1<<<432 + NPIX / 4, 256, 0, stream>>>(
        qkv_w, proj_w, fc1_w, fc2_w, wq, wp, wf1, wf2, x, ln1_w, ln1_b, h);
    // 1. QKV GEMM (single-K-shot 128x64) -> q fp32 planar (scaled) + k/v bf16 planar
    qkv_gemm<<<dim3(NPIX / 128, 9), 256, 0, stream>>>(
        h, wq, qkv_b, qbuf, kbuf, vbuf);
    // 2. neighborhood attention -> attn_b (bf16)
    attn_kernel3<<<dim3(256, NHD), 256, 0, stream>>>(qbuf, kbuf, vbuf, rpb, attn_b);
    // 3. fused tail: proj + resid + |g1| + LN2 + FC1 + GELU + FC2 + resid + |g2| -> out
    tail_fused<<<256, 512, 0, stream>>>(
        attn_b, wp, proj_b, x, gamma1, ln2_w, ln2_b,
        wf1, fc1_b, wf2, fc2_b, gamma2, quality, out);
}

// Round 4
// 170.655 us; speedup vs baseline: 1.2301x; 1.0309x over previous
//
#include <hip/hip_runtime.h>
#include <hip/hip_bf16.h>
#include <math.h>

#define DIM 192
#define NHD 6
#define HD 32
#define KSZ 7
#define HID 768
#define IMH 128
#define IMW 128
#define NPIX (IMH*IMW)
#define WIN 14
#define KPAD 40

typedef __attribute__((ext_vector_type(8))) short short8;
typedef __attribute__((ext_vector_type(4))) float f32x4;

// ---------------- weight fp32->bf16, vectorized (4 elems/thread) ----------------
__global__ __launch_bounds__(256) void cvt_w(
    const float* __restrict__ qw, const float* __restrict__ pw,
    const float* __restrict__ f1, const float* __restrict__ f2,
    __hip_bfloat16* dq, __hip_bfloat16* dp, __hip_bfloat16* df1, __hip_bfloat16* df2)
{
    int blk = blockIdx.x, t = threadIdx.x;
    const float* s; __hip_bfloat16* d; int base;
    if (blk < 108)      { s = qw; d = dq;  base = blk * 1024; }
    else if (blk < 144) { s = pw; d = dp;  base = (blk - 108) * 1024; }
    else if (blk < 288) { s = f1; d = df1; base = (blk - 144) * 1024; }
    else                { s = f2; d = df2; base = (blk - 288) * 1024; }
    int idx = base + t * 4;
    float4 v4 = *(const float4*)(s + idx);
    union { ushort4 u; __hip_bfloat16 h[4]; } o;
    o.h[0] = __float2bfloat16(v4.x); o.h[1] = __float2bfloat16(v4.y);
    o.h[2] = __float2bfloat16(v4.z); o.h[3] = __float2bfloat16(v4.w);
    *(ushort4*)&d[idx] = o.u;
}

__device__ __forceinline__ void gl_lds16(const void* g, void* l) {
    __builtin_amdgcn_global_load_lds(
        (const __attribute__((address_space(1))) void*)g,
        (__attribute__((address_space(3))) void*)l, 16, 0, 0);
}

__device__ __forceinline__ short8 cvt8(float4 a, float4 b) {
    union { short8 v; __hip_bfloat16 h[8]; } u;
    u.h[0] = __float2bfloat16(a.x); u.h[1] = __float2bfloat16(a.y);
    u.h[2] = __float2bfloat16(a.z); u.h[3] = __float2bfloat16(a.w);
    u.h[4] = __float2bfloat16(b.x); u.h[5] = __float2bfloat16(b.y);
    u.h[6] = __float2bfloat16(b.z); u.h[7] = __float2bfloat16(b.w);
    return u.v;
}

// ---------------- QKV GEMM with fused LN1: 32 rows x full 576 cols per block ----------------
// grid 512, 256 threads. LN1 computed ONCE per row (8 lanes/row), bf16 -> swizzled As (12 KB).
// wq streamed in 9 chunks of 64 n-rows through double-buffered 2x24 KB LDS with
// counted vmcnt(6) + raw s_barrier (proven skeleton from tail_fused). A-fragments hoisted
// into 24 VGPRs once; per chunk: {stage next || 12 MFMA || epilogue stores}.
__global__ __launch_bounds__(256, 2) void qkv_ln_gemm(
    const float* __restrict__ x, const float* __restrict__ lnw, const float* __restrict__ lnb,
    const __hip_bfloat16* __restrict__ W, const float* __restrict__ bias,
    float* __restrict__ qb, __hip_bfloat16* __restrict__ kb, __hip_bfloat16* __restrict__ vb)
{
    __shared__ __hip_bfloat16 As[32 * 192];      // 12 KB
    __shared__ __hip_bfloat16 Ws2[2][64 * 192];  // 2 x 24 KB
    int tid = threadIdx.x;
    int wave = tid >> 6, lane = tid & 63;
    int q = lane >> 4, col = lane & 15;
    int wm = (wave >> 1) * 16, wn = (wave & 1) * 32;
    int m0 = blockIdx.x * 32;

    auto stageW = [&](int ch, int buf) {   // 64 n-rows x 192 K, pre-swizzled source
        #pragma unroll
        for (int i = 0; i < 6; i++) {
            int c = i * 256 + tid;
            int r = c / 24, kc = c - r * 24;
            gl_lds16(W + (size_t)(ch * 64 + r) * DIM + ((kc ^ (r & 7)) * 8),
                     (char*)&Ws2[buf][0] + (i * 256 + wave * 64) * 16);
        }
    };

    stageW(0, 0);   // chunk-0 weights load under LN1 compute

    // ---- LN1: 8 lanes per row, 24 cols each ----
    {
        int row = tid >> 3, sub = tid & 7;
        const float4* xr = (const float4*)(x + (size_t)(m0 + row) * DIM + sub * 24);
        float4 xa[6];
        float s = 0.f;
        #pragma unroll
        for (int i = 0; i < 6; i++) {
            xa[i] = xr[i];
            s += xa[i].x + xa[i].y + xa[i].z + xa[i].w;
        }
        s += __shfl_xor(s, 1); s += __shfl_xor(s, 2); s += __shfl_xor(s, 4);
        float mu = s * (1.0f / DIM);
        float qs = 0.f;
        #pragma unroll
        for (int i = 0; i < 6; i++) {
            float a = xa[i].x - mu, b = xa[i].y - mu, c = xa[i].z - mu, d = xa[i].w - mu;
            qs += a * a + b * b + c * c + d * d;
        }
        qs += __shfl_xor(qs, 1); qs += __shfl_xor(qs, 2); qs += __shfl_xor(qs, 4);
        float rstd = rsqrtf(qs * (1.0f / DIM) + 1e-5f);
        const float4* wv = (const float4*)(lnw + sub * 24);
        const float4* bv = (const float4*)(lnb + sub * 24);
        #pragma unroll
        for (int j = 0; j < 3; j++) {
            float4 v0 = xa[j * 2], v1 = xa[j * 2 + 1];
            float4 w0 = wv[j * 2], w1 = wv[j * 2 + 1];
            float4 b0 = bv[j * 2], b1 = bv[j * 2 + 1];
            float4 o0, o1;
            o0.x = (v0.x - mu) * rstd * w0.x + b0.x;
            o0.y = (v0.y - mu) * rstd * w0.y + b0.y;
            o0.z = (v0.z - mu) * rstd * w0.z + b0.z;
            o0.w = (v0.w - mu) * rstd * w0.w + b0.w;
            o1.x = (v1.x - mu) * rstd * w1.x + b1.x;
            o1.y = (v1.y - mu) * rstd * w1.y + b1.y;
            o1.z = (v1.z - mu) * rstd * w1.z + b1.z;
            o1.w = (v1.w - mu) * rstd * w1.w + b1.w;
            int oct = sub * 3 + j;
            *(short8*)&As[row * 192 + ((oct ^ (row & 7)) * 8)] = cvt8(o0, o1);
        }
    }
    asm volatile("s_waitcnt lgkmcnt(0)" ::: "memory");   // my ds_writes done
    __builtin_amdgcn_s_barrier();                         // As ready for all waves

    // ---- hoist A-fragments (chunk-independent) into registers ----
    short8 af[6];
    {
        int rA = wm + col;
        #pragma unroll
        for (int ks = 0; ks < 6; ks++)
            af[ks] = *(const short8*)&As[rA * 192 + (((ks * 4 + q) ^ (rA & 7)) * 8)];
    }

    for (int ch = 0; ch < 9; ch++) {
        if (ch < 8) {
            stageW(ch + 1, (ch + 1) & 1);
            asm volatile("s_waitcnt vmcnt(6)" ::: "memory");
        } else {
            asm volatile("s_waitcnt vmcnt(0)" ::: "memory");
        }
        __builtin_amdgcn_s_barrier();
        const __hip_bfloat16* wsb = &Ws2[ch & 1][0];
        f32x4 acc[2] = {};
        #pragma unroll
        for (int ks = 0; ks < 6; ks++) {
            #pragma unroll
            for (int ni = 0; ni < 2; ni++) {
                int rB = wn + ni * 16 + col;
                short8 bf = *(const short8*)&wsb[rB * 192 + (((ks * 4 + q) ^ (rB & 7)) * 8)];
                acc[ni] = __builtin_amdgcn_mfma_f32_16x16x32_bf16(af[ks], bf, acc[ni], 0, 0, 0);
            }
        }
        #pragma unroll
        for (int ni = 0; ni < 2; ni++) {
            int n = ch * 64 + wn + ni * 16 + col;
            float bi = bias[n];
            int h18 = n >> 5;
            int sel = h18 / 6;
            int head = h18 - sel * 6;
            #pragma unroll
            for (int r4 = 0; r4 < 4; r4++) {
                int m = m0 + wm + q * 4 + r4;
                float v = acc[ni][r4] + bi;
                size_t idx = ((size_t)head * NPIX + m) * 32 + (n & 31);
                if (sel == 0)      qb[idx] = v * 0.17677669529663687f;
                else if (sel == 1) kb[idx] = __float2bfloat16(v);
                else               vb[idx] = __float2bfloat16(v);
            }
        }
        __builtin_amdgcn_s_barrier();
    }
}

// ---------------- fused tail: proj + resid + |g1| + LN2 + FC1 + GELU + FC2 + resid + |g2| ----------------
__global__ __launch_bounds__(512, 2) void tail_fused(
    const __hip_bfloat16* __restrict__ A, const __hip_bfloat16* __restrict__ Wp,
    const float* __restrict__ pb, const float* __restrict__ resid,
    const float* __restrict__ gamma1, const float* __restrict__ ln2w, const float* __restrict__ ln2b,
    const __hip_bfloat16* __restrict__ W1, const float* __restrict__ b1,
    const __hip_bfloat16* __restrict__ W2, const float* __restrict__ b2,
    const float* __restrict__ gamma2, const int* __restrict__ quality,
    float* __restrict__ outf)
{
    __shared__ __hip_bfloat16 arena[64 * 768];     // 96 KB
    __shared__ __hip_bfloat16 Wsb[2][64 * 192];    // 2 x 24 KB
    __shared__ float lnred[2][64][2];              // 1 KB
    __hip_bfloat16* Bsp = arena;                   // 72 KB: 192x192 proj weight
    __hip_bfloat16* Hs  = arena + 192 * 192;       // 24 KB: attn A-tile, then LN2(h)

    int tid = threadIdx.x;
    int wave = tid >> 6, lane = tid & 63;
    int q = lane >> 4, col = lane & 15;
    int wm = (wave >> 1) * 16, wh = wave & 1;
    int m0 = blockIdx.x * 64;

    const __hip_bfloat16* Ab = A + (size_t)m0 * DIM;
    #pragma unroll
    for (int i = 0; i < 3; i++) {
        int c = i * 512 + tid;
        int r = c / 24, kc = c - r * 24;
        gl_lds16(Ab + r * DIM + (kc ^ (r & 7)) * 8, (char*)Hs + (i * 512 + wave * 64) * 16);
    }
    #pragma unroll
    for (int i = 0; i < 9; i++) {
        int c = i * 512 + tid;
        int r = c / 24, kc = c - r * 24;
        gl_lds16(Wp + (size_t)r * DIM + (kc ^ (r & 7)) * 8, (char*)Bsp + (i * 512 + wave * 64) * 16);
    }
    __syncthreads();

    f32x4 acc[6] = {};
    #pragma unroll
    for (int ks = 0; ks < 6; ks++) {
        int rA = wm + col;
        short8 af = *(const short8*)&Hs[rA * DIM + (((ks * 4 + q) ^ (rA & 7)) * 8)];
        #pragma unroll
        for (int f = 0; f < 6; f++) {
            int rB = wh * 96 + f * 16 + col;
            short8 bf = *(const short8*)&Bsp[rB * DIM + (((ks * 4 + q) ^ (rB & 7)) * 8)];
            acc[f] = __builtin_amdgcn_mfma_f32_16x16x32_bf16(af, bf, acc[f], 0, 0, 0);
        }
    }

    int s = quality[0] - 1;
    float v[6][4];
    float sm[4] = {}, sq[4] = {};
    #pragma unroll
    for (int f = 0; f < 6; f++) {
        int n = wh * 96 + f * 16 + col;
        float bi = pb[n];
        float g = fabsf(gamma1[s * DIM + n]);
        #pragma unroll
        for (int r = 0; r < 4; r++) {
            int m = m0 + wm + q * 4 + r;
            v[f][r] = resid[(size_t)m * DIM + n] + g * (acc[f][r] + bi);
            sm[r] += v[f][r]; sq[r] += v[f][r] * v[f][r];
        }
    }
    #pragma unroll
    for (int off = 1; off <= 8; off <<= 1)
        #pragma unroll
        for (int r = 0; r < 4; r++) {
            sm[r] += __shfl_xor(sm[r], off);
            sq[r] += __shfl_xor(sq[r], off);
        }
    if (col == 0) {
        #pragma unroll
        for (int r = 0; r < 4; r++) {
            lnred[wh][wm + q * 4 + r][0] = sm[r];
            lnred[wh][wm + q * 4 + r][1] = sq[r];
        }
    }
    __syncthreads();
    float mu[4], rstd[4];
    #pragma unroll
    for (int r = 0; r < 4; r++) {
        int ml = wm + q * 4 + r;
        float smt = lnred[0][ml][0] + lnred[1][ml][0];
        float sqt = lnred[0][ml][1] + lnred[1][ml][1];
        mu[r] = smt * (1.0f / DIM);
        float var = sqt * (1.0f / DIM) - mu[r] * mu[r];
        rstd[r] = rsqrtf(var + 1e-5f);
    }
    #pragma unroll
    for (int f = 0; f < 6; f++) {
        int n = wh * 96 + f * 16 + col;
        float lw = ln2w[n], lb = ln2b[n];
        #pragma unroll
        for (int r = 0; r < 4; r++) {
            int ml = wm + q * 4 + r;
            Hs[ml * DIM + (((n >> 3) ^ (ml & 7)) * 8) + (n & 7)] =
                __float2bfloat16((v[f][r] - mu[r]) * rstd[r] * lw + lb);
        }
    }
    __syncthreads();
    short8 af1[6];
    {
        int rowA = wm + col;
        #pragma unroll
        for (int ks = 0; ks < 6; ks++)
            af1[ks] = *(const short8*)&Hs[rowA * DIM + (((ks * 4 + q) ^ (rowA & 7)) * 8)];
    }
    __syncthreads();

    auto stage1 = [&](int t, int buf) {
        #pragma unroll
        for (int i = 0; i < 3; i++) {
            int c = i * 512 + tid;
            int r = c / 24, kc = c - r * 24;
            gl_lds16(W1 + (size_t)(t * 64 + r) * DIM + (kc ^ (r & 7)) * 8,
                     (char*)&Wsb[buf][0] + (i * 512 + wave * 64) * 16);
        }
    };
    auto stage2 = [&](int ch, int buf) {
        #pragma unroll
        for (int i = 0; i < 3; i++) {
            int idx = i * 512 + tid;
            int r = idx >> 3, o = idx & 7;
            gl_lds16(W2 + (size_t)r * HID + ch * 64 + ((o ^ (r & 7)) * 8),
                     (char*)&Wsb[buf][0] + (i * 512 + wave * 64) * 16);
        }
    };
    __hip_bfloat16* Ms = arena;

    stage1(0, 0);
    for (int t = 0; t < 12; t++) {
        if (t < 11) stage1(t + 1, (t + 1) & 1);
        else        stage2(0, 0);
        asm volatile("s_waitcnt vmcnt(3)" ::: "memory");
        __builtin_amdgcn_s_barrier();
        const __hip_bfloat16* wsb = &Wsb[t & 1][0];
        f32x4 a1[2] = {};
        #pragma unroll
        for (int ks = 0; ks < 6; ks++) {
            #pragma unroll
            for (int ni = 0; ni < 2; ni++) {
                int r = wh * 32 + ni * 16 + col;
                short8 bf = *(const short8*)&wsb[r * DIM + (((ks * 4 + q) ^ (r & 7)) * 8)];
                a1[ni] = __builtin_amdgcn_mfma_f32_16x16x32_bf16(af1[ks], bf, a1[ni], 0, 0, 0);
            }
        }
        #pragma unroll
        for (int ni = 0; ni < 2; ni++) {
            int n = t * 64 + wh * 32 + ni * 16 + col;
            float bi = b1[n];
            int oct = n >> 3;
            #pragma unroll
            for (int r4 = 0; r4 < 4; r4++) {
                int row = wm + q * 4 + r4;
                float vv = a1[ni][r4] + bi;
                float u = 0.7978845608f * (vv + 0.044715f * vv * vv * vv);
                float tt = 1.f - 2.f / (__expf(2.f * u) + 1.f);
                vv = 0.5f * vv * (1.f + tt);
                int osw = (oct & ~7) | ((oct ^ row) & 7);
                *(__hip_bfloat16*)((char*)Ms + row * 1536 + osw * 16 + (n & 7) * 2) =
                    __float2bfloat16(vv);
            }
        }
        __builtin_amdgcn_s_barrier();
    }
    __syncthreads();

    int wn2 = wh * 96;
    f32x4 acc2[6] = {};
    for (int ch = 0; ch < 12; ch++) {
        stage2(ch < 11 ? ch + 1 : 11, (ch + 1) & 1);
        asm volatile("s_waitcnt vmcnt(3)" ::: "memory");
        __builtin_amdgcn_s_barrier();
        const __hip_bfloat16* wsb = &Wsb[ch & 1][0];
        #pragma unroll
        for (int ks = 0; ks < 2; ks++) {
            int row = wm + col;
            int og = ch * 8 + ks * 4 + q;
            int osw = (og & ~7) | ((og ^ row) & 7);
            short8 a2 = *(const short8*)((char*)Ms + row * 1536 + osw * 16);
            #pragma unroll
            for (int f = 0; f < 6; f++) {
                int r = wn2 + f * 16 + col;
                short8 bf = *(const short8*)&wsb[r * 64 + (((ks * 4 + q) ^ (r & 7)) * 8)];
                acc2[f] = __builtin_amdgcn_mfma_f32_16x16x32_bf16(a2, bf, acc2[f], 0, 0, 0);
            }
        }
        __builtin_amdgcn_s_barrier();
    }
    #pragma unroll
    for (int f = 0; f < 6; f++) {
        int n = wn2 + f * 16 + col;
        float g = fabsf(gamma2[s * DIM + n]);
        float bi = b2[n];
        #pragma unroll
        for (int r4 = 0; r4 < 4; r4++) {
            int m = m0 + wm + q * 4 + r4;
            outf[(size_t)m * DIM + n] = v[f][r4] + g * (acc2[f][r4] + bi);
        }
    }
}

// ---------------- Neighborhood attention: bf16 K/V, row-batched online softmax ----------------
__device__ __forceinline__ void unpack8(const __hip_bfloat16* ptr, float* f) {
    short8 s8 = *(const short8*)ptr;
    union { short8 v; unsigned u[4]; } c; c.v = s8;
    #pragma unroll
    for (int w = 0; w < 4; w++) {
        f[2*w]   = __uint_as_float(c.u[w] << 16);
        f[2*w+1] = __uint_as_float(c.u[w] & 0xffff0000u);
    }
}

__global__ __launch_bounds__(256, 4) void attn_kernel3(
    const float* __restrict__ qbuf, const __hip_bfloat16* __restrict__ kbuf,
    const __hip_bfloat16* __restrict__ vbuf, const float* __restrict__ rpb,
    __hip_bfloat16* __restrict__ out)
{
    __shared__ __hip_bfloat16 Ks[WIN * WIN * KPAD];
    __shared__ __hip_bfloat16 Vs[WIN * WIN * KPAD];
    __shared__ float rpbs[169];

    int head = blockIdx.y;
    int tile = blockIdx.x;
    int ti0 = (tile >> 4) * 8;
    int tj0 = (tile & 15) * 8;
    int wi0 = ti0 - 3; wi0 = wi0 < 0 ? 0 : (wi0 > IMH - WIN ? IMH - WIN : wi0);
    int wj0 = tj0 - 3; wj0 = wj0 < 0 ? 0 : (wj0 > IMW - WIN ? IMW - WIN : wj0);

    int tid = threadIdx.x;
    const size_t hbase = (size_t)head * NPIX;

    for (int c = tid; c < 784; c += 256) {
        int i = c / 56, part = c - i * 56;
        int n = i * WIN + (part >> 2);
        int dp = part & 3;
        size_t goff = (hbase + (size_t)(wi0 + i) * IMW + wj0) * 32 + part * 8;
        short8 kk = *(const short8*)(kbuf + goff);
        short8 vv = *(const short8*)(vbuf + goff);
        *(short8*)&Ks[n * KPAD + dp * 8] = kk;
        *(short8*)&Vs[n * KPAD + dp * 8] = vv;
    }
    if (tid < 169) rpbs[tid] = rpb[head * 169 + tid];

    int p   = tid >> 2;
    int sub = tid & 3;
    int pi = ti0 + (p >> 3), pj = tj0 + (p & 7);
    int si = pi - 3; si = si < 0 ? 0 : (si > IMH - KSZ ? IMH - KSZ : si);
    int sj = pj - 3; sj = sj < 0 ? 0 : (sj > IMW - KSZ ? IMW - KSZ : sj);
    int bi = si - wi0, bj = sj - wj0;

    const float4* qp = (const float4*)(qbuf + (hbase + (size_t)(pi * IMW + pj)) * 32 + sub * 8);
    float4 q0 = qp[0], q1 = qp[1];
    float q[8] = {q0.x, q0.y, q0.z, q0.w, q1.x, q1.y, q1.z, q1.w};

    __syncthreads();

    float m = -1e30f, l = 0.f;
    float acc[8] = {};
    #pragma unroll
    for (int ki = 0; ki < KSZ; ki++) {
        int rbase = (bi + ki) * WIN + bj;
        const float* rb = &rpbs[(si + ki - pi + 6) * 13 + (sj - pj + 6)];
        float s7[KSZ];
        #pragma unroll
        for (int kj = 0; kj < KSZ; kj++) {
            float kf[8];
            unpack8(&Ks[(rbase + kj) * KPAD + sub * 8], kf);
            float d = q[0]*kf[0] + q[1]*kf[1] + q[2]*kf[2] + q[3]*kf[3]
                    + q[4]*kf[4] + q[5]*kf[5] + q[6]*kf[6] + q[7]*kf[7];
            d += __shfl_xor(d, 1);
            d += __shfl_xor(d, 2);
            s7[kj] = d + rb[kj];
        }
        float rmax = s7[0];
        #pragma unroll
        for (int kj = 1; kj < KSZ; kj++) rmax = fmaxf(rmax, s7[kj]);
        float mn = fmaxf(m, rmax);
        float co = __expf(m - mn);
        l *= co;
        #pragma unroll
        for (int e = 0; e < 8; e++) acc[e] *= co;
        #pragma unroll
        for (int kj = 0; kj < KSZ; kj++) {
            float pw = __expf(s7[kj] - mn);
            l += pw;
            float vf[8];
            unpack8(&Vs[(rbase + kj) * KPAD + sub * 8], vf);
            #pragma unroll
            for (int e = 0; e < 8; e++) acc[e] += pw * vf[e];
        }
        m = mn;
    }
    float rl = 1.f / l;
    __hip_bfloat16* op = out + (size_t)(pi * IMW + pj) * DIM + head * HD + sub * 8;
    #pragma unroll
    for (int e = 0; e < 8; e++) op[e] = __float2bfloat16(acc[e] * rl);
}

extern "C" void kernel_launch(void* const* d_in, const int* in_sizes, int n_in,
                              void* d_out, int out_size, void* d_ws, size_t ws_size,
                              hipStream_t stream)
{
    const float* x      = (const float*)d_in[0];
    const float* qkv_w  = (const float*)d_in[1];
    const float* qkv_b  = (const float*)d_in[2];
    const float* proj_w = (const float*)d_in[3];
    const float* proj_b = (const float*)d_in[4];
    const float* rpb    = (const float*)d_in[5];
    const float* ln1_w  = (const float*)d_in[6];
    const float* ln1_b  = (const float*)d_in[7];
    const float* ln2_w  = (const float*)d_in[8];
    const float* ln2_b  = (const float*)d_in[9];
    const float* fc1_w  = (const float*)d_in[10];
    const float* fc1_b  = (const float*)d_in[11];
    const float* fc2_w  = (const float*)d_in[12];
    const float* fc2_b  = (const float*)d_in[13];
    const float* gamma1 = (const float*)d_in[14];
    const float* gamma2 = (const float*)d_in[15];
    const int*   quality= (const int*)d_in[16];
    float* out = (float*)d_out;

    char* ws = (char*)d_ws;
    float*          qbuf   = (float*)ws;                         // 12.58 MB
    __hip_bfloat16* kbuf   = (__hip_bfloat16*)(ws + 12582912);   // 6.29 MB
    __hip_bfloat16* vbuf   = (__hip_bfloat16*)(ws + 18874368);   // 6.29 MB
    __hip_bfloat16* attn_b = (__hip_bfloat16*)(ws + 44040192);
    __hip_bfloat16* wq     = (__hip_bfloat16*)(ws + 50331648);
    __hip_bfloat16* wp     = (__hip_bfloat16*)(ws + 50552832);
    __hip_bfloat16* wf1    = (__hip_bfloat16*)(ws + 50626560);
    __hip_bfloat16* wf2    = (__hip_bfloat16*)(ws + 50921472);

    // 0. weights->bf16 (vectorized, weights only)
    cvt_w<<<432, 256, 0, stream>>>(qkv_w, proj_w, fc1_w, fc2_w, wq, wp, wf1, wf2);
    // 1. QKV GEMM with fused LN1 (32 rows x full-N per block, no h round-trip)
    qkv_ln_gemm<<<512, 256, 0, stream>>>(
        x, ln1_w, ln1_b, wq, qkv_b, qbuf, kbuf, vbuf);
    // 2. neighborhood attention -> attn_b (bf16)
    attn_kernel3<<<dim3(256, NHD), 256, 0, stream>>>(qbuf, kbuf, vbuf, rpb, attn_b);
    // 3. fused tail: proj + resid + |g1| + LN2 + FC1 + GELU + FC2 + resid + |g2| -> out
    tail_fused<<<256, 512, 0, stream>>>(
        attn_b, wp, proj_b, x, gamma1, ln2_w, ln2_b,
        wf1, fc1_b, wf2, fc2_b, gamma2, quality, out);
}

// Round 5
// 170.453 us; speedup vs baseline: 1.2316x; 1.0012x over previous
//
#include <hip/hip_runtime.h>
#include <hip/hip_bf16.h>
#include <math.h>

#define DIM 192
#define NHD 6
#define HD 32
#define KSZ 7
#define HID 768
#define IMH 128
#define IMW 128
#define NPIX (IMH*IMW)
#define WIN 14
#define KPAD 40

typedef __attribute__((ext_vector_type(8))) short short8;
typedef __attribute__((ext_vector_type(4))) float f32x4;

#define LDS_SYNC() do { \
    asm volatile("s_waitcnt lgkmcnt(0)" ::: "memory"); \
    __builtin_amdgcn_sched_barrier(0); \
    __builtin_amdgcn_s_barrier(); } while (0)

// ---------------- qkv weight fp32->bf16 only (wp/wf1/wf2 ride in the attn launch) ----------------
__global__ __launch_bounds__(256) void cvt_w(
    const float* __restrict__ qw, __hip_bfloat16* __restrict__ dq)
{
    int idx = blockIdx.x * 1024 + threadIdx.x * 4;
    float4 v4 = *(const float4*)(qw + idx);
    union { ushort4 u; __hip_bfloat16 h[4]; } o;
    o.h[0] = __float2bfloat16(v4.x); o.h[1] = __float2bfloat16(v4.y);
    o.h[2] = __float2bfloat16(v4.z); o.h[3] = __float2bfloat16(v4.w);
    *(ushort4*)&dq[idx] = o.u;
}

__device__ __forceinline__ void gl_lds16(const void* g, void* l) {
    __builtin_amdgcn_global_load_lds(
        (const __attribute__((address_space(1))) void*)g,
        (__attribute__((address_space(3))) void*)l, 16, 0, 0);
}

__device__ __forceinline__ short8 cvt8(float4 a, float4 b) {
    union { short8 v; __hip_bfloat16 h[8]; } u;
    u.h[0] = __float2bfloat16(a.x); u.h[1] = __float2bfloat16(a.y);
    u.h[2] = __float2bfloat16(a.z); u.h[3] = __float2bfloat16(a.w);
    u.h[4] = __float2bfloat16(b.x); u.h[5] = __float2bfloat16(b.y);
    u.h[6] = __float2bfloat16(b.z); u.h[7] = __float2bfloat16(b.w);
    return u.v;
}

// ---- 1024-thread staging: 64 rows x 192 K (1536 slots of 16B), 96 slots/wave,
// exactly 2 VMEM issues per wave (2nd exec-masked to 32 lanes) -> uniform vmcnt.
__device__ __forceinline__ void stage_rows(const __hip_bfloat16* __restrict__ src,
                                           char* ldsbase, int wave, int lane) {
    int c0 = wave * 96 + lane;
    int r0 = c0 / 24, k0 = c0 - r0 * 24;
    gl_lds16(src + (size_t)r0 * DIM + ((k0 ^ (r0 & 7)) * 8), ldsbase + (wave * 96) * 16);
    int c1 = wave * 96 + 64 + (lane & 31);
    int r1 = c1 / 24, k1 = c1 - r1 * 24;
    if (lane < 32)
        gl_lds16(src + (size_t)r1 * DIM + ((k1 ^ (r1 & 7)) * 8), ldsbase + (wave * 96 + 64) * 16);
}
// ---- FC2 weight chunk: 192 n-rows x 64 K (8 slots/row), same 96-slot/wave split
__device__ __forceinline__ void stage_w2(const __hip_bfloat16* __restrict__ W2, int ch,
                                         char* ldsbase, int wave, int lane) {
    int i0 = wave * 96 + lane;
    int r0 = i0 >> 3, o0 = i0 & 7;
    gl_lds16(W2 + (size_t)r0 * HID + ch * 64 + ((o0 ^ (r0 & 7)) * 8), ldsbase + (wave * 96) * 16);
    int i1 = wave * 96 + 64 + (lane & 31);
    int r1 = i1 >> 3, o1 = i1 & 7;
    if (lane < 32)
        gl_lds16(W2 + (size_t)r1 * HID + ch * 64 + ((o1 ^ (r1 & 7)) * 8), ldsbase + (wave * 96 + 64) * 16);
}

// ---------------- QKV GEMM with fused LN1: 32 rows x full 576 cols per block ----------------
__global__ __launch_bounds__(256, 2) void qkv_ln_gemm(
    const float* __restrict__ x, const float* __restrict__ lnw, const float* __restrict__ lnb,
    const __hip_bfloat16* __restrict__ W, const float* __restrict__ bias,
    float* __restrict__ qb, __hip_bfloat16* __restrict__ kb, __hip_bfloat16* __restrict__ vb)
{
    __shared__ __hip_bfloat16 As[32 * 192];      // 12 KB
    __shared__ __hip_bfloat16 Ws2[2][64 * 192];  // 2 x 24 KB
    int tid = threadIdx.x;
    int wave = tid >> 6, lane = tid & 63;
    int q = lane >> 4, col = lane & 15;
    int wm = (wave >> 1) * 16, wn = (wave & 1) * 32;
    int m0 = blockIdx.x * 32;

    auto stageW = [&](int ch, int buf) {
        #pragma unroll
        for (int i = 0; i < 6; i++) {
            int c = i * 256 + tid;
            int r = c / 24, kc = c - r * 24;
            gl_lds16(W + (size_t)(ch * 64 + r) * DIM + ((kc ^ (r & 7)) * 8),
                     (char*)&Ws2[buf][0] + (i * 256 + wave * 64) * 16);
        }
    };

    stageW(0, 0);

    {
        int row = tid >> 3, sub = tid & 7;
        const float4* xr = (const float4*)(x + (size_t)(m0 + row) * DIM + sub * 24);
        float4 xa[6];
        float s = 0.f;
        #pragma unroll
        for (int i = 0; i < 6; i++) {
            xa[i] = xr[i];
            s += xa[i].x + xa[i].y + xa[i].z + xa[i].w;
        }
        s += __shfl_xor(s, 1); s += __shfl_xor(s, 2); s += __shfl_xor(s, 4);
        float mu = s * (1.0f / DIM);
        float qs = 0.f;
        #pragma unroll
        for (int i = 0; i < 6; i++) {
            float a = xa[i].x - mu, b = xa[i].y - mu, c = xa[i].z - mu, d = xa[i].w - mu;
            qs += a * a + b * b + c * c + d * d;
        }
        qs += __shfl_xor(qs, 1); qs += __shfl_xor(qs, 2); qs += __shfl_xor(qs, 4);
        float rstd = rsqrtf(qs * (1.0f / DIM) + 1e-5f);
        const float4* wv = (const float4*)(lnw + sub * 24);
        const float4* bv = (const float4*)(lnb + sub * 24);
        #pragma unroll
        for (int j = 0; j < 3; j++) {
            float4 v0 = xa[j * 2], v1 = xa[j * 2 + 1];
            float4 w0 = wv[j * 2], w1 = wv[j * 2 + 1];
            float4 b0 = bv[j * 2], b1 = bv[j * 2 + 1];
            float4 o0, o1;
            o0.x = (v0.x - mu) * rstd * w0.x + b0.x;
            o0.y = (v0.y - mu) * rstd * w0.y + b0.y;
            o0.z = (v0.z - mu) * rstd * w0.z + b0.z;
            o0.w = (v0.w - mu) * rstd * w0.w + b0.w;
            o1.x = (v1.x - mu) * rstd * w1.x + b1.x;
            o1.y = (v1.y - mu) * rstd * w1.y + b1.y;
            o1.z = (v1.z - mu) * rstd * w1.z + b1.z;
            o1.w = (v1.w - mu) * rstd * w1.w + b1.w;
            int oct = sub * 3 + j;
            *(short8*)&As[row * 192 + ((oct ^ (row & 7)) * 8)] = cvt8(o0, o1);
        }
    }
    asm volatile("s_waitcnt lgkmcnt(0)" ::: "memory");
    __builtin_amdgcn_sched_barrier(0);
    __builtin_amdgcn_s_barrier();

    short8 af[6];
    {
        int rA = wm + col;
        #pragma unroll
        for (int ks = 0; ks < 6; ks++)
            af[ks] = *(const short8*)&As[rA * 192 + (((ks * 4 + q) ^ (rA & 7)) * 8)];
    }

    for (int ch = 0; ch < 9; ch++) {
        if (ch < 8) {
            stageW(ch + 1, (ch + 1) & 1);
            asm volatile("s_waitcnt vmcnt(6)" ::: "memory");
        } else {
            asm volatile("s_waitcnt vmcnt(0)" ::: "memory");
        }
        __builtin_amdgcn_s_barrier();
        const __hip_bfloat16* wsb = &Ws2[ch & 1][0];
        f32x4 acc[2] = {};
        #pragma unroll
        for (int ks = 0; ks < 6; ks++) {
            #pragma unroll
            for (int ni = 0; ni < 2; ni++) {
                int rB = wn + ni * 16 + col;
                short8 bf = *(const short8*)&wsb[rB * 192 + (((ks * 4 + q) ^ (rB & 7)) * 8)];
                acc[ni] = __builtin_amdgcn_mfma_f32_16x16x32_bf16(af[ks], bf, acc[ni], 0, 0, 0);
            }
        }
        #pragma unroll
        for (int ni = 0; ni < 2; ni++) {
            int n = ch * 64 + wn + ni * 16 + col;
            float bi = bias[n];
            int h18 = n >> 5;
            int sel = h18 / 6;
            int head = h18 - sel * 6;
            #pragma unroll
            for (int r4 = 0; r4 < 4; r4++) {
                int m = m0 + wm + q * 4 + r4;
                float v = acc[ni][r4] + bi;
                size_t idx = ((size_t)head * NPIX + m) * 32 + (n & 31);
                if (sel == 0)      qb[idx] = v * 0.17677669529663687f;
                else if (sel == 1) kb[idx] = __float2bfloat16(v);
                else               vb[idx] = __float2bfloat16(v);
            }
        }
        __builtin_amdgcn_s_barrier();
    }
}

// ---------------- fused tail, 16 waves: proj + resid + |g1| + LN2 + FC1 + GELU + FC2 + resid + |g2| ----------------
// 64 rows/block, grid=256 (1 block/CU), 1024 threads (16 waves = 4/SIMD).
// Waves: 4 row-groups (wm) x 4 col-groups (wq4). All weights stream through Wsb 2x24KB
// (counted vmcnt(2) + raw s_barrier). Residual v[3][4] lives in registers across all 3 GEMMs.
__global__ __launch_bounds__(1024, 4) void tail_fused(
    const __hip_bfloat16* __restrict__ A, const __hip_bfloat16* __restrict__ Wp,
    const float* __restrict__ pb, const float* __restrict__ resid,
    const float* __restrict__ gamma1, const float* __restrict__ ln2w, const float* __restrict__ ln2b,
    const __hip_bfloat16* __restrict__ W1, const float* __restrict__ b1,
    const __hip_bfloat16* __restrict__ W2, const float* __restrict__ b2,
    const float* __restrict__ gamma2, const int* __restrict__ quality,
    float* __restrict__ outf)
{
    __shared__ __hip_bfloat16 arena[64 * 768];     // 96 KB: Ms; top 24 KB doubles as Hs
    __shared__ __hip_bfloat16 Wsb[2][64 * 192];    // 2 x 24 KB
    __shared__ float lnred[4][64][2];              // 2 KB
    __hip_bfloat16* Hs = arena + 36864;            // 24 KB

    int tid = threadIdx.x;
    int wave = tid >> 6, lane = tid & 63;
    int q = lane >> 4, col = lane & 15;
    int wm = (wave >> 2) * 16, wq4 = wave & 3;
    int m0 = blockIdx.x * 64;
    int s = quality[0] - 1;

    // prologue: attn tile -> Hs, proj chunk0 -> Wsb[0]
    stage_rows(A + (size_t)m0 * DIM, (char*)Hs, wave, lane);
    stage_rows(Wp, (char*)&Wsb[0][0], wave, lane);
    // phase 0
    stage_rows(Wp + 64 * DIM, (char*)&Wsb[1][0], wave, lane);
    asm volatile("s_waitcnt vmcnt(2)" ::: "memory");
    __builtin_amdgcn_s_barrier();

    short8 afp[6];
    {
        int rA = wm + col;
        #pragma unroll
        for (int ks = 0; ks < 6; ks++)
            afp[ks] = *(const short8*)&Hs[rA * 192 + (((ks * 4 + q) ^ (rA & 7)) * 8)];
    }

    float v[3][4];
    float sm[4] = {}, sq[4] = {};
    auto proj_chunk = [&](int ch, const __hip_bfloat16* wsb) {
        f32x4 pacc = {};
        int rB = wq4 * 16 + col;
        #pragma unroll
        for (int ks = 0; ks < 6; ks++) {
            short8 bf = *(const short8*)&wsb[rB * 192 + (((ks * 4 + q) ^ (rB & 7)) * 8)];
            pacc = __builtin_amdgcn_mfma_f32_16x16x32_bf16(afp[ks], bf, pacc, 0, 0, 0);
        }
        int n = ch * 64 + wq4 * 16 + col;
        float bi = pb[n];
        float g = fabsf(gamma1[s * DIM + n]);
        #pragma unroll
        for (int r = 0; r < 4; r++) {
            int m = m0 + wm + q * 4 + r;
            v[ch][r] = resid[(size_t)m * DIM + n] + g * (pacc[r] + bi);
            sm[r] += v[ch][r]; sq[r] += v[ch][r] * v[ch][r];
        }
    };

    proj_chunk(0, &Wsb[0][0]);
    __builtin_amdgcn_s_barrier();
    // phase 1
    stage_rows(Wp + 128 * DIM, (char*)&Wsb[0][0], wave, lane);
    asm volatile("s_waitcnt vmcnt(2)" ::: "memory");
    __builtin_amdgcn_s_barrier();
    proj_chunk(1, &Wsb[1][0]);
    __builtin_amdgcn_s_barrier();
    // phase 2
    stage_rows(W1, (char*)&Wsb[1][0], wave, lane);
    asm volatile("s_waitcnt vmcnt(2)" ::: "memory");
    __builtin_amdgcn_s_barrier();
    proj_chunk(2, &Wsb[0][0]);

    // ---- LN2 junction (LDS-only syncs preserve the FC1 prefetch in flight)
    #pragma unroll
    for (int off = 1; off <= 8; off <<= 1)
        #pragma unroll
        for (int r = 0; r < 4; r++) {
            sm[r] += __shfl_xor(sm[r], off);
            sq[r] += __shfl_xor(sq[r], off);
        }
    if (col == 0) {
        #pragma unroll
        for (int r = 0; r < 4; r++) {
            lnred[wq4][wm + q * 4 + r][0] = sm[r];
            lnred[wq4][wm + q * 4 + r][1] = sq[r];
        }
    }
    LDS_SYNC();
    float mu[4], rstd[4];
    #pragma unroll
    for (int r = 0; r < 4; r++) {
        int ml = wm + q * 4 + r;
        float smt = lnred[0][ml][0] + lnred[1][ml][0] + lnred[2][ml][0] + lnred[3][ml][0];
        float sqt = lnred[0][ml][1] + lnred[1][ml][1] + lnred[2][ml][1] + lnred[3][ml][1];
        mu[r] = smt * (1.0f / DIM);
        float var = sqt * (1.0f / DIM) - mu[r] * mu[r];
        rstd[r] = rsqrtf(var + 1e-5f);
    }
    #pragma unroll
    for (int ch = 0; ch < 3; ch++) {
        int n = ch * 64 + wq4 * 16 + col;
        float lw = ln2w[n], lb = ln2b[n];
        #pragma unroll
        for (int r = 0; r < 4; r++) {
            int ml = wm + q * 4 + r;
            Hs[ml * 192 + (((n >> 3) ^ (ml & 7)) * 8) + (n & 7)] =
                __float2bfloat16((v[ch][r] - mu[r]) * rstd[r] * lw + lb);
        }
    }
    LDS_SYNC();
    short8 af1[6];
    {
        int rowA = wm + col;
        #pragma unroll
        for (int ks = 0; ks < 6; ks++)
            af1[ks] = *(const short8*)&Hs[rowA * 192 + (((ks * 4 + q) ^ (rowA & 7)) * 8)];
    }
    LDS_SYNC();   // af1 in regs before Ms overwrites arena

    // ---------------- FC1 phase (12 chunks) ----------------
    for (int t = 0; t < 12; t++) {
        if (t < 11) stage_rows(W1 + (size_t)(t + 1) * 64 * DIM, (char*)&Wsb[t & 1][0], wave, lane);
        else        stage_w2(W2, 0, (char*)&Wsb[1][0], wave, lane);
        asm volatile("s_waitcnt vmcnt(2)" ::: "memory");
        __builtin_amdgcn_s_barrier();
        const __hip_bfloat16* wsb = &Wsb[(t + 1) & 1][0];
        f32x4 a1 = {};
        int rB = wq4 * 16 + col;
        #pragma unroll
        for (int ks = 0; ks < 6; ks++) {
            short8 bf = *(const short8*)&wsb[rB * 192 + (((ks * 4 + q) ^ (rB & 7)) * 8)];
            a1 = __builtin_amdgcn_mfma_f32_16x16x32_bf16(af1[ks], bf, a1, 0, 0, 0);
        }
        int n = t * 64 + wq4 * 16 + col;
        float bi = b1[n];
        int oct = n >> 3;
        #pragma unroll
        for (int r4 = 0; r4 < 4; r4++) {
            int row = wm + q * 4 + r4;
            float vv = a1[r4] + bi;
            float u = 0.7978845608f * (vv + 0.044715f * vv * vv * vv);
            float tt = 1.f - 2.f / (__expf(2.f * u) + 1.f);
            vv = 0.5f * vv * (1.f + tt);
            int osw = (oct & ~7) | ((oct ^ row) & 7);
            *(__hip_bfloat16*)((char*)arena + row * 1536 + osw * 16 + (n & 7) * 2) =
                __float2bfloat16(vv);
        }
        __builtin_amdgcn_s_barrier();
    }
    LDS_SYNC();   // all Ms writes visible

    // ---------------- FC2 phase (12 chunks) ----------------
    f32x4 acc2[3] = {};
    for (int ch = 0; ch < 12; ch++) {
        if (ch < 11) {
            stage_w2(W2, ch + 1, (char*)&Wsb[ch & 1][0], wave, lane);
            asm volatile("s_waitcnt vmcnt(2)" ::: "memory");
        } else {
            asm volatile("s_waitcnt vmcnt(0)" ::: "memory");
        }
        __builtin_amdgcn_s_barrier();
        const __hip_bfloat16* wsb = &Wsb[(ch + 1) & 1][0];
        #pragma unroll
        for (int ks = 0; ks < 2; ks++) {
            int row = wm + col;
            int og = ch * 8 + ks * 4 + q;
            int osw = (og & ~7) | ((og ^ row) & 7);
            short8 a2 = *(const short8*)((char*)arena + row * 1536 + osw * 16);
            #pragma unroll
            for (int f = 0; f < 3; f++) {
                int rB = f * 64 + wq4 * 16 + col;
                short8 bf = *(const short8*)&wsb[rB * 64 + (((ks * 4 + q) ^ (rB & 7)) * 8)];
                acc2[f] = __builtin_amdgcn_mfma_f32_16x16x32_bf16(a2, bf, acc2[f], 0, 0, 0);
            }
        }
        __builtin_amdgcn_s_barrier();
    }

    // ---- final: out = v + |g2|*(fc2+b2)  (v in registers, col sets identical to proj's)
    #pragma unroll
    for (int f = 0; f < 3; f++) {
        int n = f * 64 + wq4 * 16 + col;
        float g = fabsf(gamma2[s * DIM + n]);
        float bi = b2[n];
        #pragma unroll
        for (int r4 = 0; r4 < 4; r4++) {
            int m = m0 + wm + q * 4 + r4;
            outf[(size_t)m * DIM + n] = v[f][r4] + g * (acc2[f][r4] + bi);
        }
    }
}

// ---------------- Neighborhood attention (+ piggybacked wp/wf1/wf2 cvt blocks) ----------------
__device__ __forceinline__ void unpack8(const __hip_bfloat16* ptr, float* f) {
    short8 s8 = *(const short8*)ptr;
    union { short8 v; unsigned u[4]; } c; c.v = s8;
    #pragma unroll
    for (int w = 0; w < 4; w++) {
        f[2*w]   = __uint_as_float(c.u[w] << 16);
        f[2*w+1] = __uint_as_float(c.u[w] & 0xffff0000u);
    }
}

__global__ __launch_bounds__(256, 4) void attn_kernel3(
    const float* __restrict__ qbuf, const __hip_bfloat16* __restrict__ kbuf,
    const __hip_bfloat16* __restrict__ vbuf, const float* __restrict__ rpb,
    __hip_bfloat16* __restrict__ out,
    const float* __restrict__ pw, const float* __restrict__ f1w, const float* __restrict__ f2w,
    __hip_bfloat16* __restrict__ dp, __hip_bfloat16* __restrict__ df1, __hip_bfloat16* __restrict__ df2)
{
    if (blockIdx.x >= 256) {
        // weight-cvt blocks, hidden under attention (outputs needed only by tail_fused)
        if (blockIdx.y != 0) return;
        int blk = blockIdx.x - 256, t = threadIdx.x;
        const float* s; __hip_bfloat16* d; int base;
        if (blk < 36)       { s = pw;  d = dp;  base = blk * 1024; }
        else if (blk < 180) { s = f1w; d = df1; base = (blk - 36) * 1024; }
        else                { s = f2w; d = df2; base = (blk - 180) * 1024; }
        int idx = base + t * 4;
        float4 v4 = *(const float4*)(s + idx);
        union { ushort4 u; __hip_bfloat16 h[4]; } o;
        o.h[0] = __float2bfloat16(v4.x); o.h[1] = __float2bfloat16(v4.y);
        o.h[2] = __float2bfloat16(v4.z); o.h[3] = __float2bfloat16(v4.w);
        *(ushort4*)&d[idx] = o.u;
        return;
    }

    __shared__ __hip_bfloat16 Ks[WIN * WIN * KPAD];
    __shared__ __hip_bfloat16 Vs[WIN * WIN * KPAD];
    __shared__ float rpbs[169];

    int head = blockIdx.y;
    int tile = blockIdx.x;
    int ti0 = (tile >> 4) * 8;
    int tj0 = (tile & 15) * 8;
    int wi0 = ti0 - 3; wi0 = wi0 < 0 ? 0 : (wi0 > IMH - WIN ? IMH - WIN : wi0);
    int wj0 = tj0 - 3; wj0 = wj0 < 0 ? 0 : (wj0 > IMW - WIN ? IMW - WIN : wj0);

    int tid = threadIdx.x;
    const size_t hbase = (size_t)head * NPIX;

    for (int c = tid; c < 784; c += 256) {
        int i = c / 56, part = c - i * 56;
        int n = i * WIN + (part >> 2);
        int dp2 = part & 3;
        size_t goff = (hbase + (size_t)(wi0 + i) * IMW + wj0) * 32 + part * 8;
        short8 kk = *(const short8*)(kbuf + goff);
        short8 vv = *(const short8*)(vbuf + goff);
        *(short8*)&Ks[n * KPAD + dp2 * 8] = kk;
        *(short8*)&Vs[n * KPAD + dp2 * 8] = vv;
    }
    if (tid < 169) rpbs[tid] = rpb[head * 169 + tid];

    int p   = tid >> 2;
    int sub = tid & 3;
    int pi = ti0 + (p >> 3), pj = tj0 + (p & 7);
    int si = pi - 3; si = si < 0 ? 0 : (si > IMH - KSZ ? IMH - KSZ : si);
    int sj = pj - 3; sj = sj < 0 ? 0 : (sj > IMW - KSZ ? IMW - KSZ : sj);
    int bi = si - wi0, bj = sj - wj0;

    const float4* qp = (const float4*)(qbuf + (hbase + (size_t)(pi * IMW + pj)) * 32 + sub * 8);
    float4 q0 = qp[0], q1 = qp[1];
    float q[8] = {q0.x, q0.y, q0.z, q0.w, q1.x, q1.y, q1.z, q1.w};

    __syncthreads();

    float m = -1e30f, l = 0.f;
    float acc[8] = {};
    #pragma unroll
    for (int ki = 0; ki < KSZ; ki++) {
        int rbase = (bi + ki) * WIN + bj;
        const float* rb = &rpbs[(si + ki - pi + 6) * 13 + (sj - pj + 6)];
        float s7[KSZ];
        #pragma unroll
        for (int kj = 0; kj < KSZ; kj++) {
            float kf[8];
            unpack8(&Ks[(rbase + kj) * KPAD + sub * 8], kf);
            float d = q[0]*kf[0] + q[1]*kf[1] + q[2]*kf[2] + q[3]*kf[3]
                    + q[4]*kf[4] + q[5]*kf[5] + q[6]*kf[6] + q[7]*kf[7];
            d += __shfl_xor(d, 1);
            d += __shfl_xor(d, 2);
            s7[kj] = d + rb[kj];
        }
        float rmax = s7[0];
        #pragma unroll
        for (int kj = 1; kj < KSZ; kj++) rmax = fmaxf(rmax, s7[kj]);
        float mn = fmaxf(m, rmax);
        float co = __expf(m - mn);
        l *= co;
        #pragma unroll
        for (int e = 0; e < 8; e++) acc[e] *= co;
        #pragma unroll
        for (int kj = 0; kj < KSZ; kj++) {
            float pw2 = __expf(s7[kj] - mn);
            l += pw2;
            float vf[8];
            unpack8(&Vs[(rbase + kj) * KPAD + sub * 8], vf);
            #pragma unroll
            for (int e = 0; e < 8; e++) acc[e] += pw2 * vf[e];
        }
        m = mn;
    }
    float rl = 1.f / l;
    __hip_bfloat16* op = out + (size_t)(pi * IMW + pj) * DIM + head * HD + sub * 8;
    #pragma unroll
    for (int e = 0; e < 8; e++) op[e] = __float2bfloat16(acc[e] * rl);
}

extern "C" void kernel_launch(void* const* d_in, const int* in_sizes, int n_in,
                              void* d_out, int out_size, void* d_ws, size_t ws_size,
                              hipStream_t stream)
{
    const float* x      = (const float*)d_in[0];
    const float* qkv_w  = (const float*)d_in[1];
    const float* qkv_b  = (const float*)d_in[2];
    const float* proj_w = (const float*)d_in[3];
    const float* proj_b = (const float*)d_in[4];
    const float* rpb    = (const float*)d_in[5];
    const float* ln1_w  = (const float*)d_in[6];
    const float* ln1_b  = (const float*)d_in[7];
    const float* ln2_w  = (const float*)d_in[8];
    const float* ln2_b  = (const float*)d_in[9];
    const float* fc1_w  = (const float*)d_in[10];
    const float* fc1_b  = (const float*)d_in[11];
    const float* fc2_w  = (const float*)d_in[12];
    const float* fc2_b  = (const float*)d_in[13];
    const float* gamma1 = (const float*)d_in[14];
    const float* gamma2 = (const float*)d_in[15];
    const int*   quality= (const int*)d_in[16];
    float* out = (float*)d_out;

    char* ws = (char*)d_ws;
    float*          qbuf   = (float*)ws;                         // 12.58 MB
    __hip_bfloat16* kbuf   = (__hip_bfloat16*)(ws + 12582912);   // 6.29 MB
    __hip_bfloat16* vbuf   = (__hip_bfloat16*)(ws + 18874368);   // 6.29 MB
    __hip_bfloat16* attn_b = (__hip_bfloat16*)(ws + 44040192);
    __hip_bfloat16* wq     = (__hip_bfloat16*)(ws + 50331648);
    __hip_bfloat16* wp     = (__hip_bfloat16*)(ws + 50552832);
    __hip_bfloat16* wf1    = (__hip_bfloat16*)(ws + 50626560);
    __hip_bfloat16* wf2    = (__hip_bfloat16*)(ws + 50921472);

    // 0. qkv weights->bf16 only (108 blocks)
    cvt_w<<<108, 256, 0, stream>>>(qkv_w, wq);
    // 1. QKV GEMM with fused LN1
    qkv_ln_gemm<<<512, 256, 0, stream>>>(
        x, ln1_w, ln1_b, wq, qkv_b, qbuf, kbuf, vbuf);
    // 2. neighborhood attention (+324 piggyback blocks converting wp/wf1/wf2)
    attn_kernel3<<<dim3(256 + 324, NHD), 256, 0, stream>>>(
        qbuf, kbuf, vbuf, rpb, attn_b, proj_w, fc1_w, fc2_w, wp, wf1, wf2);
    // 3. fused tail (16 waves): proj + resid + |g1| + LN2 + FC1 + GELU + FC2 + resid + |g2|
    tail_fused<<<256, 1024, 0, stream>>>(
        attn_b, wp, proj_b, x, gamma1, ln2_w, ln2_b,
        wf1, fc1_b, wf2, fc2_b, gamma2, quality, out);
}